// Round 13
// baseline (64.204 us; speedup 1.0000x reference)
//
#include <hip/hip_runtime.h>
#include <hip/hip_fp16.h>

#define G_ 20000
#define W_ 8
#define K_ 16
#define T_ 1500
#define B_ 256
#define D_ 2

// transpose_feat tiles: ceil(1500/32)=47 x 256/32=8
#define TF_TX 47
#define TF_BLOCKS (TF_TX * 8)

#define PAIRS_PER_BLOCK 8   // 16 groups per block -> full 64B out lines

// ---- packed per-GROUP-PAIR record (2 groups), byte offsets ----
#define REC_BYTES 2432
#define REC_U32   608
#define OFF_A1    0
#define OFF_AM0   512
#define OFF_AM1   1024
#define OFF_AF    1536
#define OFF_B1    2048
#define OFF_BM0   2112
#define OFF_BM1   2176
#define OFF_BF    2240
#define OFF_IDX0  2304
#define OFF_IDX1  2368

using h4  = __attribute__((ext_vector_type(4))) __fp16;
using f4v = __attribute__((ext_vector_type(4))) float;
typedef decltype(__builtin_amdgcn_cvt_pkrtz(0.0f, 0.0f)) v2h;

__device__ __forceinline__ unsigned pack_h2(float lo, float hi) {
    __half l = __float2half(lo), h = __float2half(hi);   // RTE
    return ((unsigned)__half_as_ushort(h) << 16) | __half_as_ushort(l);
}

// ---------- fused prep kernel (unchanged from round 12) ----------
__global__ __launch_bounds__(256) void prep_kernel(
    const float* __restrict__ feat,
    float* __restrict__ featT,
    const int*   __restrict__ tf_idx,
    const float* __restrict__ W1,
    const float* __restrict__ b1,
    const float* __restrict__ Wm,
    const float* __restrict__ bm,
    const float* __restrict__ Wf,
    const float* __restrict__ bf,
    unsigned* __restrict__ pack)
{
    const int bid = blockIdx.x;
    const int tid = threadIdx.x;
    if (bid < TF_BLOCKS) {
        __shared__ float tile[32][33];
        int t0 = (bid % TF_TX) * 32;
        int b0 = (bid / TF_TX) * 32;
        int tx = tid & 31, ty = tid >> 5;      // (32,8)
        #pragma unroll
        for (int i = 0; i < 32; i += 8) {
            int bb = b0 + ty + i, tt = t0 + tx;
            if (tt < T_) tile[ty + i][tx] = feat[bb * T_ + tt];
        }
        __syncthreads();
        #pragma unroll
        for (int i = 0; i < 32; i += 8) {
            int tt = t0 + ty + i, bb = b0 + tx;
            if (tt < T_) featT[tt * B_ + bb] = tile[tx][ty + i];
        }
        return;
    }
    const int p  = bid - TF_BLOCKS;
    const int g0 = 2 * p, g1 = 2 * p + 1;
    const float LOG2E = 1.44269504088896340736f;
    const float SCALE = 1.0507009873554805f;
    const float SL    = SCALE * LOG2E;
    unsigned* rec = pack + (long)p * REC_U32;
    for (int s = tid; s < REC_U32; s += 256) {
        unsigned u;
        if (s < 128) {                       // A1 (merged W1 pair)
            int row = s >> 3, k0 = (s & 7) * 2;
            const float* wp = (row < 8)
                ? W1 + ((long)g0 * W_ + row) * K_ + k0
                : W1 + ((long)g1 * W_ + (row - 8)) * K_ + k0;
            u = pack_h2(LOG2E * wp[0], LOG2E * wp[1]);
        } else if (s < 384) {                // AM0 / AM1 block-diag
            int r = s - 128, d = r >> 7; r &= 127;
            int row = r >> 3, k0 = (r & 7) * 2;
            float w0 = 0.f, w1 = 0.f;
            if (row < 8 && k0 < 8) {
                const float* wp = Wm + (((long)d * G_ + g0) * W_ + row) * W_ + k0;
                w0 = SL * wp[0]; w1 = SL * wp[1];
            } else if (row >= 8 && k0 >= 8) {
                const float* wp = Wm + (((long)d * G_ + g1) * W_ + (row - 8)) * W_ + (k0 - 8);
                w0 = SL * wp[0]; w1 = SL * wp[1];
            }
            u = pack_h2(w0, w1);
        } else if (s < 512) {                // AF
            int r = s - 384, row = r >> 3, k0 = (r & 7) * 2;
            float w0 = 0.f, w1 = 0.f;
            if (row == 0 && k0 < 8) {
                const float* wp = Wf + (long)g0 * W_ + k0;
                w0 = SCALE * wp[0]; w1 = SCALE * wp[1];
            } else if (row == 8 && k0 >= 8) {
                const float* wp = Wf + (long)g1 * W_ + (k0 - 8);
                w0 = SCALE * wp[0]; w1 = SCALE * wp[1];
            }
            u = pack_h2(w0, w1);
        } else if (s < 528) {                // bias1 (16 f32, row order)
            int row = s - 512;
            float v = (row < 8) ? LOG2E * b1[g0 * W_ + row]
                                : LOG2E * b1[g1 * W_ + row - 8];
            u = __float_as_uint(v);
        } else if (s < 560) {                // biasm d=0,1
            int r = s - 528, d = r >> 4, row = r & 15;
            float v = (row < 8) ? LOG2E * bm[((long)d * G_ + g0) * W_ + row]
                                : LOG2E * bm[((long)d * G_ + g1) * W_ + row - 8];
            u = __float_as_uint(v);
        } else if (s < 576) {                // biasf
            int row = s - 560;
            float v = (row == 0) ? bf[g0] : (row == 8) ? bf[g1] : 0.f;
            u = __float_as_uint(v);
        } else if (s < 592) {                // idx g0 (byte offsets)
            u = (unsigned)(tf_idx[g0 * K_ + (s - 576)] << 10);
        } else {                             // idx g1
            u = (unsigned)(tf_idx[g1 * K_ + (s - 592)] << 10);
        }
        rec[s] = u;
    }
}

// ---------- main MFMA kernel (fused output transpose) ----------

__device__ __forceinline__ float selu_u(float u) {
    const float ALPHA = 1.6732632423543772f;
    const float LN2   = 0.6931471805599453f;
    float e = __builtin_amdgcn_exp2f(u);
    float m = fmaf(ALPHA, e, -ALPHA);
    return fmaf(fmaxf(u, 0.0f), LN2, fminf(m, 0.0f));
}

__device__ __forceinline__ unsigned cvtpk_u(float a, float b) {
    v2h t = __builtin_amdgcn_cvt_pkrtz(a, b);
    unsigned u; __builtin_memcpy(&u, &t, 4);
    return u;
}

__device__ __forceinline__ f4v mfma16(uint2 a, uint2 b, f4v c) {
    h4 ah, bh;
    __builtin_memcpy(&ah, &a, 8);
    __builtin_memcpy(&bh, &b, 8);
    return __builtin_amdgcn_mfma_f32_16x16x16f16(ah, bh, c, 0, 0, 0);
}

// Block = 256 threads (4 waves) = 16 consecutive groups x all 256 batch.
// Wave wv owns batch rows [64wv, 64wv+64); loops over 8 group-pairs running
// the round-12 verified mfma chain; results staged in LDS [256][17] (17
// coprime 32 -> conflict-free), then each thread writes ONE full aligned
// 64B line out[b][g0..g0+15] -> no outT buffer, no transpose kernel.
__global__ __launch_bounds__(256, 5) void decoder_mfma(
    const float* __restrict__ featT,    // (T,B)
    const unsigned* __restrict__ pack,  // (G/2, REC_U32)
    float* __restrict__ out)            // (B,G)
{
    const int tid  = threadIdx.x;
    const int lane = tid & 63;
    const int wv   = tid >> 6;
    const int p0   = blockIdx.x * PAIRS_PER_BLOCK;
    const char* fc = (const char*)featT;

    const int col  = lane & 15;            // A-row / B-col / C-col
    const int q    = lane >> 4;            // k/row quad
    const int foff = col * 32 + q * 8;     // A frag: [row=col][k=4q..4q+3]
    const bool rlt8 = col < 8;

    __shared__ float smem[256][17];

    #pragma unroll 1
    for (int pp = 0; pp < PAIRS_PER_BLOCK; ++pp) {
        const char* R = (const char*)pack + (long)(p0 + pp) * REC_BYTES;

        uint2 A1  = *(const uint2*)(R + OFF_A1  + foff);
        uint2 AM0 = *(const uint2*)(R + OFF_AM0 + foff);
        uint2 AM1 = *(const uint2*)(R + OFF_AM1 + foff);
        uint2 AF  = *(const uint2*)(R + OFF_AF  + foff);
        uint2 A1g0, A1g1;                  // split merged W1: disjoint halves
        A1g0.x = rlt8 ? A1.x : 0u;  A1g0.y = rlt8 ? A1.y : 0u;
        A1g1.x = rlt8 ? 0u : A1.x;  A1g1.y = rlt8 ? 0u : A1.y;

        f4v bias1 = *(const f4v*)(R + OFF_B1  + q * 16);
        f4v bm0   = *(const f4v*)(R + OFF_BM0 + q * 16);
        f4v bm1   = *(const f4v*)(R + OFF_BM1 + q * 16);
        f4v bfin  = *(const f4v*)(R + OFF_BF  + q * 16);
        int4 id0  = *(const int4*)(R + OFF_IDX0 + q * 16);
        int4 id1  = *(const int4*)(R + OFF_IDX1 + q * 16);

        #pragma unroll
        for (int t = 0; t < 4; ++t) {
            const int bb = wv * 64 + t * 16;
            const int vb = (bb + col) * 4;

            float x0 = *(const float*)(fc + id0.x + vb);
            float x1 = *(const float*)(fc + id0.y + vb);
            float x2 = *(const float*)(fc + id0.z + vb);
            float x3 = *(const float*)(fc + id0.w + vb);
            float y0 = *(const float*)(fc + id1.x + vb);
            float y1 = *(const float*)(fc + id1.y + vb);
            float y2 = *(const float*)(fc + id1.z + vb);
            float y3 = *(const float*)(fc + id1.w + vb);
            uint2 bg0, bg1;
            bg0.x = cvtpk_u(x0, x1); bg0.y = cvtpk_u(x2, x3);
            bg1.x = cvtpk_u(y0, y1); bg1.y = cvtpk_u(y2, y3);

            f4v acc = mfma16(A1g0, bg0, bias1);
            acc     = mfma16(A1g1, bg1, acc);

            uint2 bh;
            bh.x = cvtpk_u(selu_u(acc[0]), selu_u(acc[1]));
            bh.y = cvtpk_u(selu_u(acc[2]), selu_u(acc[3]));

            acc  = mfma16(AM0, bh, bm0);
            bh.x = cvtpk_u(selu_u(acc[0]), selu_u(acc[1]));
            bh.y = cvtpk_u(selu_u(acc[2]), selu_u(acc[3]));

            acc  = mfma16(AM1, bh, bm1);
            bh.x = cvtpk_u(selu_u(acc[0]), selu_u(acc[1]));
            bh.y = cvtpk_u(selu_u(acc[2]), selu_u(acc[3]));

            acc = mfma16(AF, bh, bfin);

            // D row0 (g even) in lanes q==0, row8 (g odd) in q==2
            if (!(q & 1))
                smem[bb + col][2 * pp + ((q >> 1) & 1)] = acc[0];
        }
    }

    __syncthreads();

    // epilogue: thread b writes one full aligned 64B line out[b][16 groups]
    {
        const int b = tid;
        float* orow = out + (long)b * G_ + (long)blockIdx.x * 16;
        #pragma unroll
        for (int j = 0; j < 4; ++j) {
            float4 v = make_float4(smem[b][4 * j + 0], smem[b][4 * j + 1],
                                   smem[b][4 * j + 2], smem[b][4 * j + 3]);
            ((float4*)orow)[j] = v;
        }
    }
}

// ---------- fallbacks (small workspace) ----------
#define FGPB 4
__device__ __forceinline__ float selu_f(float x) {
    const float scale = 1.0507009873554805f;
    const float sa    = 1.7580993408473766f;
    float e   = __expf(x);
    float neg = fmaf(sa, e, -sa);
    return x > 0.0f ? scale * x : neg;
}
template<bool TRANSPOSED>
__global__ __launch_bounds__(256) void decoder_kernel(
    const float* __restrict__ featsrc, const int* __restrict__ tf_idx,
    const float* __restrict__ W1, const float* __restrict__ b1,
    const float* __restrict__ Wm, const float* __restrict__ bm,
    const float* __restrict__ Wf, const float* __restrict__ bf,
    float* __restrict__ out)
{
    const int b  = threadIdx.x;
    const int g0 = blockIdx.x * FGPB;
    float res[FGPB];
    #pragma unroll
    for (int gi = 0; gi < FGPB; ++gi) {
        const int g = g0 + gi;
        float xg[K_];
        #pragma unroll
        for (int k = 0; k < K_; ++k) {
            int t = tf_idx[g * K_ + k];
            xg[k] = TRANSPOSED ? featsrc[t * B_ + b] : featsrc[b * T_ + t];
        }
        float h[W_];
        #pragma unroll
        for (int w = 0; w < W_; ++w) {
            float acc = b1[g * W_ + w];
            #pragma unroll
            for (int k = 0; k < K_; ++k)
                acc = fmaf(xg[k], W1[(g * W_ + w) * K_ + k], acc);
            h[w] = selu_f(acc);
        }
        #pragma unroll
        for (int d = 0; d < D_; ++d) {
            const float* wmd = Wm + ((size_t)d * G_ + g) * (W_ * W_);
            const float* bmd = bm + ((size_t)d * G_ + g) * W_;
            float h2[W_];
            #pragma unroll
            for (int v = 0; v < W_; ++v) {
                float acc = bmd[v];
                #pragma unroll
                for (int w = 0; w < W_; ++w)
                    acc = fmaf(h[w], wmd[v * W_ + w], acc);
                h2[v] = selu_f(acc);
            }
            #pragma unroll
            for (int w = 0; w < W_; ++w) h[w] = h2[w];
        }
        float acc = bf[g];
        #pragma unroll
        for (int w = 0; w < W_; ++w)
            acc = fmaf(h[w], Wf[g * W_ + w], acc);
        res[gi] = acc;
    }
    float4* o = (float4*)(out + (size_t)b * G_ + g0);
    o[0] = make_float4(res[0], res[1], res[2], res[3]);
}

extern "C" void kernel_launch(void* const* d_in, const int* in_sizes, int n_in,
                              void* d_out, int out_size, void* d_ws, size_t ws_size,
                              hipStream_t stream) {
    const float* feat   = (const float*)d_in[0];
    const int*   tf_idx = (const int*)  d_in[1];
    const float* W1     = (const float*)d_in[2];
    const float* b1     = (const float*)d_in[3];
    const float* Wm     = (const float*)d_in[4];
    const float* bm     = (const float*)d_in[5];
    const float* Wf     = (const float*)d_in[6];
    const float* bf     = (const float*)d_in[7];
    float* out = (float*)d_out;

    const size_t featT_b = (size_t)T_ * B_ * sizeof(float);          // 1.536 MB
    const size_t pack_b  = (size_t)(G_ / 2) * REC_BYTES;             // 24.32 MB

    if (ws_size >= featT_b + pack_b) {
        float*    featT = (float*)d_ws;
        unsigned* packp = (unsigned*)((char*)d_ws + featT_b);

        hipLaunchKernelGGL(prep_kernel, dim3(TF_BLOCKS + G_ / 2), dim3(256), 0,
                           stream, feat, featT, tf_idx, W1, b1, Wm, bm, Wf, bf,
                           packp);

        hipLaunchKernelGGL(decoder_mfma, dim3(G_ / (2 * PAIRS_PER_BLOCK)),
                           dim3(256), 0, stream, featT, packp, out);
    } else if (ws_size >= featT_b) {
        float* featT = (float*)d_ws;
        hipLaunchKernelGGL(prep_kernel, dim3(TF_BLOCKS), dim3(256), 0,
                           stream, feat, featT, tf_idx, W1, b1, Wm, bm, Wf, bf,
                           (unsigned*)featT /*unused pack*/);
        hipLaunchKernelGGL((decoder_kernel<true>), dim3(G_ / FGPB), dim3(B_), 0,
                           stream, featT, tf_idx, W1, b1, Wm, bm, Wf, bf, out);
    } else {
        hipLaunchKernelGGL((decoder_kernel<false>), dim3(G_ / FGPB), dim3(B_), 0,
                           stream, feat, tf_idx, W1, b1, Wm, bm, Wf, bf, out);
    }
}

// Round 14
// 58.412 us; speedup vs baseline: 1.0992x; 1.0992x over previous
//
#include <hip/hip_runtime.h>
#include <hip/hip_fp16.h>

#define G_ 20000
#define W_ 8
#define K_ 16
#define T_ 1500
#define B_ 256
#define D_ 2

// transpose_feat tiles: ceil(1500/32)=47 x 256/32=8
#define TF_TX 47
#define TF_BLOCKS (TF_TX * 8)

// ---- packed per-GROUP-PAIR record (2 groups), byte offsets ----
#define REC_BYTES 2432
#define REC_U32   608
#define OFF_A1    0
#define OFF_AM0   512
#define OFF_AM1   1024
#define OFF_AF    1536
#define OFF_B1    2048
#define OFF_BM0   2112
#define OFF_BM1   2176
#define OFF_BF    2240
#define OFF_IDX0  2304
#define OFF_IDX1  2368

using h4  = __attribute__((ext_vector_type(4))) __fp16;
using f4v = __attribute__((ext_vector_type(4))) float;
typedef decltype(__builtin_amdgcn_cvt_pkrtz(0.0f, 0.0f)) v2h;

__device__ __forceinline__ unsigned pack_h2(float lo, float hi) {
    __half l = __float2half(lo), h = __float2half(hi);   // RTE
    return ((unsigned)__half_as_ushort(h) << 16) | __half_as_ushort(l);
}

// ---------- fused prep kernel (unchanged from round 12) ----------
__global__ __launch_bounds__(256) void prep_kernel(
    const float* __restrict__ feat,
    float* __restrict__ featT,
    const int*   __restrict__ tf_idx,
    const float* __restrict__ W1,
    const float* __restrict__ b1,
    const float* __restrict__ Wm,
    const float* __restrict__ bm,
    const float* __restrict__ Wf,
    const float* __restrict__ bf,
    unsigned* __restrict__ pack)
{
    const int bid = blockIdx.x;
    const int tid = threadIdx.x;
    if (bid < TF_BLOCKS) {
        __shared__ float tile[32][33];
        int t0 = (bid % TF_TX) * 32;
        int b0 = (bid / TF_TX) * 32;
        int tx = tid & 31, ty = tid >> 5;      // (32,8)
        #pragma unroll
        for (int i = 0; i < 32; i += 8) {
            int bb = b0 + ty + i, tt = t0 + tx;
            if (tt < T_) tile[ty + i][tx] = feat[bb * T_ + tt];
        }
        __syncthreads();
        #pragma unroll
        for (int i = 0; i < 32; i += 8) {
            int tt = t0 + ty + i, bb = b0 + tx;
            if (tt < T_) featT[tt * B_ + bb] = tile[tx][ty + i];
        }
        return;
    }
    const int p  = bid - TF_BLOCKS;
    const int g0 = 2 * p, g1 = 2 * p + 1;
    const float LOG2E = 1.44269504088896340736f;
    const float SCALE = 1.0507009873554805f;
    const float SL    = SCALE * LOG2E;
    unsigned* rec = pack + (long)p * REC_U32;
    for (int s = tid; s < REC_U32; s += 256) {
        unsigned u;
        if (s < 128) {                       // A1 (merged W1 pair)
            int row = s >> 3, k0 = (s & 7) * 2;
            const float* wp = (row < 8)
                ? W1 + ((long)g0 * W_ + row) * K_ + k0
                : W1 + ((long)g1 * W_ + (row - 8)) * K_ + k0;
            u = pack_h2(LOG2E * wp[0], LOG2E * wp[1]);
        } else if (s < 384) {                // AM0 / AM1 block-diag
            int r = s - 128, d = r >> 7; r &= 127;
            int row = r >> 3, k0 = (r & 7) * 2;
            float w0 = 0.f, w1 = 0.f;
            if (row < 8 && k0 < 8) {
                const float* wp = Wm + (((long)d * G_ + g0) * W_ + row) * W_ + k0;
                w0 = SL * wp[0]; w1 = SL * wp[1];
            } else if (row >= 8 && k0 >= 8) {
                const float* wp = Wm + (((long)d * G_ + g1) * W_ + (row - 8)) * W_ + (k0 - 8);
                w0 = SL * wp[0]; w1 = SL * wp[1];
            }
            u = pack_h2(w0, w1);
        } else if (s < 512) {                // AF
            int r = s - 384, row = r >> 3, k0 = (r & 7) * 2;
            float w0 = 0.f, w1 = 0.f;
            if (row == 0 && k0 < 8) {
                const float* wp = Wf + (long)g0 * W_ + k0;
                w0 = SCALE * wp[0]; w1 = SCALE * wp[1];
            } else if (row == 8 && k0 >= 8) {
                const float* wp = Wf + (long)g1 * W_ + (k0 - 8);
                w0 = SCALE * wp[0]; w1 = SCALE * wp[1];
            }
            u = pack_h2(w0, w1);
        } else if (s < 528) {                // bias1 (16 f32, row order)
            int row = s - 512;
            float v = (row < 8) ? LOG2E * b1[g0 * W_ + row]
                                : LOG2E * b1[g1 * W_ + row - 8];
            u = __float_as_uint(v);
        } else if (s < 560) {                // biasm d=0,1
            int r = s - 528, d = r >> 4, row = r & 15;
            float v = (row < 8) ? LOG2E * bm[((long)d * G_ + g0) * W_ + row]
                                : LOG2E * bm[((long)d * G_ + g1) * W_ + row - 8];
            u = __float_as_uint(v);
        } else if (s < 576) {                // biasf
            int row = s - 560;
            float v = (row == 0) ? bf[g0] : (row == 8) ? bf[g1] : 0.f;
            u = __float_as_uint(v);
        } else if (s < 592) {                // idx g0 (byte offsets)
            u = (unsigned)(tf_idx[g0 * K_ + (s - 576)] << 10);
        } else {                             // idx g1
            u = (unsigned)(tf_idx[g1 * K_ + (s - 592)] << 10);
        }
        rec[s] = u;
    }
}

// ---------- main MFMA kernel (fused output transpose, batch-split grid) ----------

__device__ __forceinline__ float selu_u(float u) {
    const float ALPHA = 1.6732632423543772f;
    const float LN2   = 0.6931471805599453f;
    float e = __builtin_amdgcn_exp2f(u);
    float m = fmaf(ALPHA, e, -ALPHA);
    return fmaf(fmaxf(u, 0.0f), LN2, fminf(m, 0.0f));
}

__device__ __forceinline__ unsigned cvtpk_u(float a, float b) {
    v2h t = __builtin_amdgcn_cvt_pkrtz(a, b);
    unsigned u; __builtin_memcpy(&u, &t, 4);
    return u;
}

__device__ __forceinline__ f4v mfma16(uint2 a, uint2 b, f4v c) {
    h4 ah, bh;
    __builtin_memcpy(&ah, &a, 8);
    __builtin_memcpy(&bh, &b, 8);
    return __builtin_amdgcn_mfma_f32_16x16x16f16(ah, bh, c, 0, 0, 0);
}

// Grid (G/16, B/64) = (1250, 4) -> 5000 blocks = 20000 waves (round 13's
// fused kernel had only 1250 blocks -> 35% occupancy; this restores the
// 20000-wave regime that measured ~70% in rounds 7/11).
// Block = 256 threads (4 waves) = 16 consecutive groups x 64 batch rows.
// Wave wv runs pairs {2wv, 2wv+1}, each over 4 batch-tiles of 16
// (4 independent chains interleave -> ILP). Results staged in LDS[64][17],
// then 4 threads per row write one full aligned 64B line of out(B,G).
__global__ __launch_bounds__(256, 8) void decoder_mfma(
    const float* __restrict__ featT,    // (T,B)
    const unsigned* __restrict__ pack,  // (G/2, REC_U32)
    float* __restrict__ out)            // (B,G)
{
    const int tid  = threadIdx.x;
    const int lane = tid & 63;
    const int wv   = tid >> 6;
    const int gc   = blockIdx.x;           // group-chunk of 16
    const int bq   = blockIdx.y;           // batch quarter (64 rows)
    const int p0   = gc * 8;
    const char* fc = (const char*)featT;

    const int col  = lane & 15;            // A-row / B-col / C-col
    const int q    = lane >> 4;            // k/row quad
    const int foff = col * 32 + q * 8;     // A frag: [row=col][k=4q..4q+3]
    const bool rlt8 = col < 8;

    __shared__ float smem[64][17];

    #pragma unroll 1
    for (int i = 0; i < 2; ++i) {
        const int pp = 2 * wv + i;
        const char* R = (const char*)pack + (long)(p0 + pp) * REC_BYTES;

        uint2 A1  = *(const uint2*)(R + OFF_A1  + foff);
        uint2 AM0 = *(const uint2*)(R + OFF_AM0 + foff);
        uint2 AM1 = *(const uint2*)(R + OFF_AM1 + foff);
        uint2 AF  = *(const uint2*)(R + OFF_AF  + foff);
        uint2 A1g0, A1g1;                  // split merged W1: disjoint halves
        A1g0.x = rlt8 ? A1.x : 0u;  A1g0.y = rlt8 ? A1.y : 0u;
        A1g1.x = rlt8 ? 0u : A1.x;  A1g1.y = rlt8 ? 0u : A1.y;

        f4v bias1 = *(const f4v*)(R + OFF_B1  + q * 16);
        f4v bm0   = *(const f4v*)(R + OFF_BM0 + q * 16);
        f4v bm1   = *(const f4v*)(R + OFF_BM1 + q * 16);
        f4v bfin  = *(const f4v*)(R + OFF_BF  + q * 16);
        int4 id0  = *(const int4*)(R + OFF_IDX0 + q * 16);
        int4 id1  = *(const int4*)(R + OFF_IDX1 + q * 16);

        #pragma unroll
        for (int t = 0; t < 4; ++t) {
            const int bb = bq * 64 + t * 16;
            const int vb = (bb + col) * 4;

            float x0 = *(const float*)(fc + id0.x + vb);
            float x1 = *(const float*)(fc + id0.y + vb);
            float x2 = *(const float*)(fc + id0.z + vb);
            float x3 = *(const float*)(fc + id0.w + vb);
            float y0 = *(const float*)(fc + id1.x + vb);
            float y1 = *(const float*)(fc + id1.y + vb);
            float y2 = *(const float*)(fc + id1.z + vb);
            float y3 = *(const float*)(fc + id1.w + vb);
            uint2 bg0, bg1;
            bg0.x = cvtpk_u(x0, x1); bg0.y = cvtpk_u(x2, x3);
            bg1.x = cvtpk_u(y0, y1); bg1.y = cvtpk_u(y2, y3);

            f4v acc = mfma16(A1g0, bg0, bias1);
            acc     = mfma16(A1g1, bg1, acc);

            uint2 bh;
            bh.x = cvtpk_u(selu_u(acc[0]), selu_u(acc[1]));
            bh.y = cvtpk_u(selu_u(acc[2]), selu_u(acc[3]));

            acc  = mfma16(AM0, bh, bm0);
            bh.x = cvtpk_u(selu_u(acc[0]), selu_u(acc[1]));
            bh.y = cvtpk_u(selu_u(acc[2]), selu_u(acc[3]));

            acc  = mfma16(AM1, bh, bm1);
            bh.x = cvtpk_u(selu_u(acc[0]), selu_u(acc[1]));
            bh.y = cvtpk_u(selu_u(acc[2]), selu_u(acc[3]));

            acc = mfma16(AF, bh, bfin);

            // D row0 (g even) in lanes q==0, row8 (g odd) in q==2
            if (!(q & 1))
                smem[t * 16 + col][2 * pp + ((q >> 1) & 1)] = acc[0];
        }
    }

    __syncthreads();

    // epilogue: 4 threads per batch row write one full aligned 64B line
    {
        const int row = tid >> 2;          // 0..63 (local batch row)
        const int seg = tid & 3;           // 16B segment within the line
        float4 v = make_float4(smem[row][seg * 4 + 0], smem[row][seg * 4 + 1],
                               smem[row][seg * 4 + 2], smem[row][seg * 4 + 3]);
        *(float4*)(out + (long)(bq * 64 + row) * G_ + gc * 16 + seg * 4) = v;
    }
}

// ---------- fallbacks (small workspace) ----------
#define FGPB 4
__device__ __forceinline__ float selu_f(float x) {
    const float scale = 1.0507009873554805f;
    const float sa    = 1.7580993408473766f;
    float e   = __expf(x);
    float neg = fmaf(sa, e, -sa);
    return x > 0.0f ? scale * x : neg;
}
template<bool TRANSPOSED>
__global__ __launch_bounds__(256) void decoder_kernel(
    const float* __restrict__ featsrc, const int* __restrict__ tf_idx,
    const float* __restrict__ W1, const float* __restrict__ b1,
    const float* __restrict__ Wm, const float* __restrict__ bm,
    const float* __restrict__ Wf, const float* __restrict__ bf,
    float* __restrict__ out)
{
    const int b  = threadIdx.x;
    const int g0 = blockIdx.x * FGPB;
    float res[FGPB];
    #pragma unroll
    for (int gi = 0; gi < FGPB; ++gi) {
        const int g = g0 + gi;
        float xg[K_];
        #pragma unroll
        for (int k = 0; k < K_; ++k) {
            int t = tf_idx[g * K_ + k];
            xg[k] = TRANSPOSED ? featsrc[t * B_ + b] : featsrc[b * T_ + t];
        }
        float h[W_];
        #pragma unroll
        for (int w = 0; w < W_; ++w) {
            float acc = b1[g * W_ + w];
            #pragma unroll
            for (int k = 0; k < K_; ++k)
                acc = fmaf(xg[k], W1[(g * W_ + w) * K_ + k], acc);
            h[w] = selu_f(acc);
        }
        #pragma unroll
        for (int d = 0; d < D_; ++d) {
            const float* wmd = Wm + ((size_t)d * G_ + g) * (W_ * W_);
            const float* bmd = bm + ((size_t)d * G_ + g) * W_;
            float h2[W_];
            #pragma unroll
            for (int v = 0; v < W_; ++v) {
                float acc = bmd[v];
                #pragma unroll
                for (int w = 0; w < W_; ++w)
                    acc = fmaf(h[w], wmd[v * W_ + w], acc);
                h2[v] = selu_f(acc);
            }
            #pragma unroll
            for (int w = 0; w < W_; ++w) h[w] = h2[w];
        }
        float acc = bf[g];
        #pragma unroll
        for (int w = 0; w < W_; ++w)
            acc = fmaf(h[w], Wf[g * W_ + w], acc);
        res[gi] = acc;
    }
    float4* o = (float4*)(out + (size_t)b * G_ + g0);
    o[0] = make_float4(res[0], res[1], res[2], res[3]);
}

extern "C" void kernel_launch(void* const* d_in, const int* in_sizes, int n_in,
                              void* d_out, int out_size, void* d_ws, size_t ws_size,
                              hipStream_t stream) {
    const float* feat   = (const float*)d_in[0];
    const int*   tf_idx = (const int*)  d_in[1];
    const float* W1     = (const float*)d_in[2];
    const float* b1     = (const float*)d_in[3];
    const float* Wm     = (const float*)d_in[4];
    const float* bm     = (const float*)d_in[5];
    const float* Wf     = (const float*)d_in[6];
    const float* bf     = (const float*)d_in[7];
    float* out = (float*)d_out;

    const size_t featT_b = (size_t)T_ * B_ * sizeof(float);          // 1.536 MB
    const size_t pack_b  = (size_t)(G_ / 2) * REC_BYTES;             // 24.32 MB

    if (ws_size >= featT_b + pack_b) {
        float*    featT = (float*)d_ws;
        unsigned* packp = (unsigned*)((char*)d_ws + featT_b);

        hipLaunchKernelGGL(prep_kernel, dim3(TF_BLOCKS + G_ / 2), dim3(256), 0,
                           stream, feat, featT, tf_idx, W1, b1, Wm, bm, Wf, bf,
                           packp);

        hipLaunchKernelGGL(decoder_mfma, dim3(G_ / 16, B_ / 64), dim3(256), 0,
                           stream, featT, packp, out);
    } else if (ws_size >= featT_b) {
        float* featT = (float*)d_ws;
        hipLaunchKernelGGL(prep_kernel, dim3(TF_BLOCKS), dim3(256), 0,
                           stream, feat, featT, tf_idx, W1, b1, Wm, bm, Wf, bf,
                           (unsigned*)featT /*unused pack*/);
        hipLaunchKernelGGL((decoder_kernel<true>), dim3(G_ / FGPB), dim3(B_), 0,
                           stream, featT, tf_idx, W1, b1, Wm, bm, Wf, bf, out);
    } else {
        hipLaunchKernelGGL((decoder_kernel<false>), dim3(G_ / FGPB), dim3(B_), 0,
                           stream, feat, tf_idx, W1, b1, Wm, bm, Wf, bf, out);
    }
}

// Round 15
// 53.543 us; speedup vs baseline: 1.1991x; 1.0910x over previous
//
#include <hip/hip_runtime.h>
#include <hip/hip_fp16.h>

#define G_ 20000
#define W_ 8
#define K_ 16
#define T_ 1500
#define B_ 256
#define D_ 2

using h4  = __attribute__((ext_vector_type(4))) __fp16;
using f4v = __attribute__((ext_vector_type(4))) float;
typedef decltype(__builtin_amdgcn_cvt_pkrtz(0.0f, 0.0f)) v2h;

// ---------- prep: feat (B,T) -> featT (T,B) ----------
__global__ void transpose_feat(const float* __restrict__ feat,
                               float* __restrict__ featT) {
    __shared__ float tile[32][33];
    int t0 = blockIdx.x * 32;
    int b0 = blockIdx.y * 32;
    int tx = threadIdx.x, ty = threadIdx.y;  // block (32,8)
    #pragma unroll
    for (int i = 0; i < 32; i += 8) {
        int bb = b0 + ty + i, tt = t0 + tx;
        if (tt < T_) tile[ty + i][tx] = feat[bb * T_ + tt];
    }
    __syncthreads();
    #pragma unroll
    for (int i = 0; i < 32; i += 8) {
        int tt = t0 + ty + i, bb = b0 + tx;
        if (tt < T_) featT[tt * B_ + bb] = tile[tx][ty + i];
    }
}

// ---------- main MFMA kernel: fragments built from RAW arrays ----------

__device__ __forceinline__ float selu_u(float u) {
    const float ALPHA = 1.6732632423543772f;
    const float LN2   = 0.6931471805599453f;
    float e = __builtin_amdgcn_exp2f(u);
    float m = fmaf(ALPHA, e, -ALPHA);
    return fmaf(fmaxf(u, 0.0f), LN2, fminf(m, 0.0f));
}

__device__ __forceinline__ unsigned cvtpk_u(float a, float b) {
    v2h t = __builtin_amdgcn_cvt_pkrtz(a, b);
    unsigned u; __builtin_memcpy(&u, &t, 4);
    return u;
}

__device__ __forceinline__ f4v mfma16(uint2 a, uint2 b, f4v c) {
    h4 ah, bh;
    __builtin_memcpy(&ah, &a, 8);
    __builtin_memcpy(&bh, &b, 8);
    return __builtin_amdgcn_mfma_f32_16x16x16f16(ah, bh, c, 0, 0, 0);
}

// Grid (B/64, G/16) = (4,1250): the 4 batch-quarter blocks that share a
// group-chunk's weights are dispatch-adjacent (L2/L3 locality).
// Block = 256 threads (4 waves) = 16 consecutive groups x 64 batch rows.
// Wave wv runs pairs {2wv, 2wv+1}; per pair, each lane builds its MFMA
// A/bias/idx fragments directly from raw W1/Wm/Wf/b*/tf_idx (aligned 16B
// lane loads + scale + cvt_pkrtz + mask) — the round-12..14 pack kernel
// (10000 blocks, ~50MB traffic, ~13us serialized) is eliminated.
// Chain identity (verified r12): D frag (row=(l>>4)*4+r, col=l&15) == next
// B frag (k=(l>>4)*4+j, col=l&15) -> selu+cvt in-register between layers.
__global__ __launch_bounds__(256, 6) void decoder_mfma(
    const float* __restrict__ featT,    // (T,B)
    const int*   __restrict__ tf_idx,   // (G,K)
    const float* __restrict__ W1,       // (G,W,K)
    const float* __restrict__ b1,       // (G,W)
    const float* __restrict__ Wm,       // (D,G,W,W)
    const float* __restrict__ bm,       // (D,G,W)
    const float* __restrict__ Wf,       // (G,W)
    const float* __restrict__ bf,       // (G,)
    float* __restrict__ out)            // (B,G)
{
    const float LOG2E = 1.44269504088896340736f;
    const float SCALE = 1.0507009873554805f;
    const float SL    = SCALE * LOG2E;

    const int tid  = threadIdx.x;
    const int lane = tid & 63;
    const int wv   = tid >> 6;
    const int bq   = blockIdx.x;           // batch quarter (64 rows)
    const int gc   = blockIdx.y;           // group-chunk of 16
    const char* fc = (const char*)featT;

    const int col   = lane & 15;           // A-row / B-col / C-col
    const int q     = lane >> 4;           // k/row quad
    const bool rlt8 = col < 8;
    const int kq    = (q & 1) * 4;         // k-offset within an 8-wide row

    __shared__ float smem[64][17];

    #pragma unroll 1
    for (int i = 0; i < 2; ++i) {
        const int pp = 2 * wv + i;         // pair within chunk (0..7)
        const int p  = gc * 8 + pp;
        const int g0 = 2 * p, g1 = 2 * p + 1;
        const int ga = rlt8 ? g0 : g1;     // row-side group (A-row = col)
        const int ra = rlt8 ? col : col - 8;
        const int gq = (q < 2) ? g0 : g1;  // row-quad-side group (C rows)

        // --- A1: rows0-7 = LOG2E*W1_g0[w][k], rows8-15 = g1; split halves ---
        float4 w1v = *(const float4*)(W1 + ((long)ga * W_ + ra) * K_ + 4 * q);
        uint2 af;
        af.x = cvtpk_u(LOG2E * w1v.x, LOG2E * w1v.y);
        af.y = cvtpk_u(LOG2E * w1v.z, LOG2E * w1v.w);
        uint2 A1g0, A1g1;
        A1g0.x = rlt8 ? af.x : 0u;  A1g0.y = rlt8 ? af.y : 0u;
        A1g1.x = rlt8 ? 0u : af.x;  A1g1.y = rlt8 ? 0u : af.y;

        // --- AM0/AM1 block-diag: nonzero iff (col<8)==(q<2) ---
        const bool diag = (rlt8 == (q < 2));
        float4 wm0v = *(const float4*)(Wm + ((long)0 * G_ + ga) * 64 + ra * 8 + kq);
        float4 wm1v = *(const float4*)(Wm + ((long)1 * G_ + ga) * 64 + ra * 8 + kq);
        uint2 AM0, AM1;
        AM0.x = diag ? cvtpk_u(SL * wm0v.x, SL * wm0v.y) : 0u;
        AM0.y = diag ? cvtpk_u(SL * wm0v.z, SL * wm0v.w) : 0u;
        AM1.x = diag ? cvtpk_u(SL * wm1v.x, SL * wm1v.y) : 0u;
        AM1.y = diag ? cvtpk_u(SL * wm1v.z, SL * wm1v.w) : 0u;

        // --- AF: row0 = SCALE*Wf_g0 (k0-7); row8 = SCALE*Wf_g1 (k8-15) ---
        const bool fnz = (ra == 0) && diag;
        float4 wfv = *(const float4*)(Wf + (long)ga * W_ + kq);
        uint2 AF;
        AF.x = fnz ? cvtpk_u(SCALE * wfv.x, SCALE * wfv.y) : 0u;
        AF.y = fnz ? cvtpk_u(SCALE * wfv.z, SCALE * wfv.w) : 0u;

        // --- bias C-in frags (rows 4q..4q+3) ---
        float4 b1v  = *(const float4*)(b1 + (long)gq * W_ + kq);
        float4 bm0v = *(const float4*)(bm + ((long)0 * G_ + gq) * W_ + kq);
        float4 bm1v = *(const float4*)(bm + ((long)1 * G_ + gq) * W_ + kq);
        f4v bias1 = {LOG2E * b1v.x,  LOG2E * b1v.y,  LOG2E * b1v.z,  LOG2E * b1v.w};
        f4v bmf0  = {LOG2E * bm0v.x, LOG2E * bm0v.y, LOG2E * bm0v.z, LOG2E * bm0v.w};
        f4v bmf1  = {LOG2E * bm1v.x, LOG2E * bm1v.y, LOG2E * bm1v.z, LOG2E * bm1v.w};
        f4v bfin  = {0.f, 0.f, 0.f, 0.f};
        bfin[0] = ((q & 1) == 0) ? bf[gq] : 0.0f;   // rows 0 (g0) and 8 (g1)

        // --- idx frags: byte offsets t*B_*4 ---
        int4 id0 = *(const int4*)(tf_idx + g0 * K_ + 4 * q);
        int4 id1 = *(const int4*)(tf_idx + g1 * K_ + 4 * q);
        id0.x <<= 10; id0.y <<= 10; id0.z <<= 10; id0.w <<= 10;
        id1.x <<= 10; id1.y <<= 10; id1.z <<= 10; id1.w <<= 10;

        #pragma unroll
        for (int t = 0; t < 4; ++t) {
            const int bb = bq * 64 + t * 16;
            const int vb = (bb + col) * 4;

            float x0 = *(const float*)(fc + id0.x + vb);
            float x1 = *(const float*)(fc + id0.y + vb);
            float x2 = *(const float*)(fc + id0.z + vb);
            float x3 = *(const float*)(fc + id0.w + vb);
            float y0 = *(const float*)(fc + id1.x + vb);
            float y1 = *(const float*)(fc + id1.y + vb);
            float y2 = *(const float*)(fc + id1.z + vb);
            float y3 = *(const float*)(fc + id1.w + vb);
            uint2 bg0, bg1;
            bg0.x = cvtpk_u(x0, x1); bg0.y = cvtpk_u(x2, x3);
            bg1.x = cvtpk_u(y0, y1); bg1.y = cvtpk_u(y2, y3);

            f4v acc = mfma16(A1g0, bg0, bias1);
            acc     = mfma16(A1g1, bg1, acc);

            uint2 bh;
            bh.x = cvtpk_u(selu_u(acc[0]), selu_u(acc[1]));
            bh.y = cvtpk_u(selu_u(acc[2]), selu_u(acc[3]));

            acc  = mfma16(AM0, bh, bmf0);
            bh.x = cvtpk_u(selu_u(acc[0]), selu_u(acc[1]));
            bh.y = cvtpk_u(selu_u(acc[2]), selu_u(acc[3]));

            acc  = mfma16(AM1, bh, bmf1);
            bh.x = cvtpk_u(selu_u(acc[0]), selu_u(acc[1]));
            bh.y = cvtpk_u(selu_u(acc[2]), selu_u(acc[3]));

            acc = mfma16(AF, bh, bfin);

            // D row0 (g even) in lanes q==0, row8 (g odd) in q==2
            if (!(q & 1))
                smem[t * 16 + col][2 * pp + ((q >> 1) & 1)] = acc[0];
        }
    }

    __syncthreads();

    // epilogue: 4 threads per batch row write one full aligned 64B line
    {
        const int row = tid >> 2;          // 0..63 (local batch row)
        const int seg = tid & 3;           // 16B segment within the line
        float4 v = make_float4(smem[row][seg * 4 + 0], smem[row][seg * 4 + 1],
                               smem[row][seg * 4 + 2], smem[row][seg * 4 + 3]);
        *(float4*)(out + (long)(bq * 64 + row) * G_ + gc * 16 + seg * 4) = v;
    }
}

// ---------- fallback (no workspace): direct scalar path ----------
#define FGPB 4
__device__ __forceinline__ float selu_f(float x) {
    const float scale = 1.0507009873554805f;
    const float sa    = 1.7580993408473766f;
    float e   = __expf(x);
    float neg = fmaf(sa, e, -sa);
    return x > 0.0f ? scale * x : neg;
}
template<bool TRANSPOSED>
__global__ __launch_bounds__(256) void decoder_kernel(
    const float* __restrict__ featsrc, const int* __restrict__ tf_idx,
    const float* __restrict__ W1, const float* __restrict__ b1,
    const float* __restrict__ Wm, const float* __restrict__ bm,
    const float* __restrict__ Wf, const float* __restrict__ bf,
    float* __restrict__ out)
{
    const int b  = threadIdx.x;
    const int g0 = blockIdx.x * FGPB;
    float res[FGPB];
    #pragma unroll
    for (int gi = 0; gi < FGPB; ++gi) {
        const int g = g0 + gi;
        float xg[K_];
        #pragma unroll
        for (int k = 0; k < K_; ++k) {
            int t = tf_idx[g * K_ + k];
            xg[k] = TRANSPOSED ? featsrc[t * B_ + b] : featsrc[b * T_ + t];
        }
        float h[W_];
        #pragma unroll
        for (int w = 0; w < W_; ++w) {
            float acc = b1[g * W_ + w];
            #pragma unroll
            for (int k = 0; k < K_; ++k)
                acc = fmaf(xg[k], W1[(g * W_ + w) * K_ + k], acc);
            h[w] = selu_f(acc);
        }
        #pragma unroll
        for (int d = 0; d < D_; ++d) {
            const float* wmd = Wm + ((size_t)d * G_ + g) * (W_ * W_);
            const float* bmd = bm + ((size_t)d * G_ + g) * W_;
            float h2[W_];
            #pragma unroll
            for (int v = 0; v < W_; ++v) {
                float acc = bmd[v];
                #pragma unroll
                for (int w = 0; w < W_; ++w)
                    acc = fmaf(h[w], wmd[v * W_ + w], acc);
                h2[v] = selu_f(acc);
            }
            #pragma unroll
            for (int w = 0; w < W_; ++w) h[w] = h2[w];
        }
        float acc = bf[g];
        #pragma unroll
        for (int w = 0; w < W_; ++w)
            acc = fmaf(h[w], Wf[g * W_ + w], acc);
        res[gi] = acc;
    }
    float4* o = (float4*)(out + (size_t)b * G_ + g0);
    o[0] = make_float4(res[0], res[1], res[2], res[3]);
}

extern "C" void kernel_launch(void* const* d_in, const int* in_sizes, int n_in,
                              void* d_out, int out_size, void* d_ws, size_t ws_size,
                              hipStream_t stream) {
    const float* feat   = (const float*)d_in[0];
    const int*   tf_idx = (const int*)  d_in[1];
    const float* W1     = (const float*)d_in[2];
    const float* b1     = (const float*)d_in[3];
    const float* Wm     = (const float*)d_in[4];
    const float* bm     = (const float*)d_in[5];
    const float* Wf     = (const float*)d_in[6];
    const float* bf     = (const float*)d_in[7];
    float* out = (float*)d_out;

    const size_t featT_b = (size_t)T_ * B_ * sizeof(float);   // 1.536 MB

    if (ws_size >= featT_b) {
        float* featT = (float*)d_ws;
        hipLaunchKernelGGL(transpose_feat, dim3((T_ + 31) / 32, B_ / 32),
                           dim3(32, 8), 0, stream, feat, featT);
        hipLaunchKernelGGL(decoder_mfma, dim3(B_ / 64, G_ / 16), dim3(256), 0,
                           stream, featT, tf_idx, W1, b1, Wm, bm, Wf, bf, out);
    } else {
        hipLaunchKernelGGL((decoder_kernel<false>), dim3(G_ / FGPB), dim3(B_), 0,
                           stream, feat, tf_idx, W1, b1, Wm, bm, Wf, bf, out);
    }
}

// Round 16
// 53.204 us; speedup vs baseline: 1.2067x; 1.0064x over previous
//
#include <hip/hip_runtime.h>
#include <hip/hip_fp16.h>

#define G_ 20000
#define W_ 8
#define K_ 16
#define T_ 1500
#define B_ 256
#define D_ 2

using h4  = __attribute__((ext_vector_type(4))) __fp16;
using f4v = __attribute__((ext_vector_type(4))) float;
typedef decltype(__builtin_amdgcn_cvt_pkrtz(0.0f, 0.0f)) v2h;

// ---------- prep: feat (B,T) -> featT (T,B) ----------
__global__ void transpose_feat(const float* __restrict__ feat,
                               float* __restrict__ featT) {
    __shared__ float tile[32][33];
    int t0 = blockIdx.x * 32;
    int b0 = blockIdx.y * 32;
    int tx = threadIdx.x, ty = threadIdx.y;  // block (32,8)
    #pragma unroll
    for (int i = 0; i < 32; i += 8) {
        int bb = b0 + ty + i, tt = t0 + tx;
        if (tt < T_) tile[ty + i][tx] = feat[bb * T_ + tt];
    }
    __syncthreads();
    #pragma unroll
    for (int i = 0; i < 32; i += 8) {
        int tt = t0 + ty + i, bb = b0 + tx;
        if (tt < T_) featT[tt * B_ + bb] = tile[tx][ty + i];
    }
}

// ---------- main MFMA kernel ----------

__device__ __forceinline__ float selu_u(float u) {
    const float ALPHA = 1.6732632423543772f;
    const float LN2   = 0.6931471805599453f;
    float e = __builtin_amdgcn_exp2f(u);
    float m = fmaf(ALPHA, e, -ALPHA);
    return fmaf(fmaxf(u, 0.0f), LN2, fminf(m, 0.0f));
}

__device__ __forceinline__ unsigned cvtpk_u(float a, float b) {
    v2h t = __builtin_amdgcn_cvt_pkrtz(a, b);
    unsigned u; __builtin_memcpy(&u, &t, 4);
    return u;
}

__device__ __forceinline__ f4v mfma16(uint2 a, uint2 b, f4v c) {
    h4 ah, bh;
    __builtin_memcpy(&ah, &a, 8);
    __builtin_memcpy(&bh, &b, 8);
    return __builtin_amdgcn_mfma_f32_16x16x16f16(ah, bh, c, 0, 0, 0);
}

// Grid (B/64, G/16) = (4,1250), block = 512 threads = 8 waves.
// r15 lesson: 4-wave blocks with 2 pairs/wave -> 20000 waves (2.44 fills,
// 51% occupancy, long tail). Now ONE pair per wave, 8 waves/block ->
// 40000 waves (4.9 fills) at identical total VALU work: frag-build count
// unchanged (1/wave vs 2/wave at half the waves), chains unchanged.
// Per pair, each lane builds its MFMA A/bias/idx fragments directly from
// raw W1/Wm/Wf/b*/tf_idx (aligned 16B lane loads + scale + cvt_pkrtz +
// mask). Chain identity (verified r12): D frag == next layer's B frag.
__global__ __launch_bounds__(512, 8) void decoder_mfma(
    const float* __restrict__ featT,    // (T,B)
    const int*   __restrict__ tf_idx,   // (G,K)
    const float* __restrict__ W1,       // (G,W,K)
    const float* __restrict__ b1,       // (G,W)
    const float* __restrict__ Wm,       // (D,G,W,W)
    const float* __restrict__ bm,       // (D,G,W)
    const float* __restrict__ Wf,       // (G,W)
    const float* __restrict__ bf,       // (G,)
    float* __restrict__ out)            // (B,G)
{
    const float LOG2E = 1.44269504088896340736f;
    const float SCALE = 1.0507009873554805f;
    const float SL    = SCALE * LOG2E;

    const int tid  = threadIdx.x;
    const int lane = tid & 63;
    const int wv   = tid >> 6;              // 0..7 = pair within chunk
    const int bq   = blockIdx.x;             // batch quarter (64 rows)
    const int gc   = blockIdx.y;             // group-chunk of 16
    const char* fc = (const char*)featT;

    const int col   = lane & 15;             // A-row / B-col / C-col
    const int q     = lane >> 4;             // k/row quad
    const bool rlt8 = col < 8;
    const int kq    = (q & 1) * 4;           // k-offset within an 8-wide row

    __shared__ float smem[64][17];

    {
        const int pp = wv;
        const int p  = gc * 8 + pp;
        const int g0 = 2 * p, g1 = 2 * p + 1;
        const int ga = rlt8 ? g0 : g1;       // row-side group (A-row = col)
        const int ra = rlt8 ? col : col - 8;
        const int gq = (q < 2) ? g0 : g1;    // row-quad-side group (C rows)

        // --- A1: rows0-7 = LOG2E*W1_g0[w][k], rows8-15 = g1; split halves ---
        float4 w1v = *(const float4*)(W1 + ((long)ga * W_ + ra) * K_ + 4 * q);
        uint2 af;
        af.x = cvtpk_u(LOG2E * w1v.x, LOG2E * w1v.y);
        af.y = cvtpk_u(LOG2E * w1v.z, LOG2E * w1v.w);
        uint2 A1g0, A1g1;
        A1g0.x = rlt8 ? af.x : 0u;  A1g0.y = rlt8 ? af.y : 0u;
        A1g1.x = rlt8 ? 0u : af.x;  A1g1.y = rlt8 ? 0u : af.y;

        // --- AM0/AM1 block-diag: nonzero iff (col<8)==(q<2) ---
        const bool diag = (rlt8 == (q < 2));
        float4 wm0v = *(const float4*)(Wm + ((long)0 * G_ + ga) * 64 + ra * 8 + kq);
        float4 wm1v = *(const float4*)(Wm + ((long)1 * G_ + ga) * 64 + ra * 8 + kq);
        uint2 AM0, AM1;
        AM0.x = diag ? cvtpk_u(SL * wm0v.x, SL * wm0v.y) : 0u;
        AM0.y = diag ? cvtpk_u(SL * wm0v.z, SL * wm0v.w) : 0u;
        AM1.x = diag ? cvtpk_u(SL * wm1v.x, SL * wm1v.y) : 0u;
        AM1.y = diag ? cvtpk_u(SL * wm1v.z, SL * wm1v.w) : 0u;

        // --- AF: row0 = SCALE*Wf_g0 (k0-7); row8 = SCALE*Wf_g1 (k8-15) ---
        const bool fnz = (ra == 0) && diag;
        float4 wfv = *(const float4*)(Wf + (long)ga * W_ + kq);
        uint2 AF;
        AF.x = fnz ? cvtpk_u(SCALE * wfv.x, SCALE * wfv.y) : 0u;
        AF.y = fnz ? cvtpk_u(SCALE * wfv.z, SCALE * wfv.w) : 0u;

        // --- bias C-in frags (rows 4q..4q+3) ---
        float4 b1v  = *(const float4*)(b1 + (long)gq * W_ + kq);
        float4 bm0v = *(const float4*)(bm + ((long)0 * G_ + gq) * W_ + kq);
        float4 bm1v = *(const float4*)(bm + ((long)1 * G_ + gq) * W_ + kq);
        f4v bias1 = {LOG2E * b1v.x,  LOG2E * b1v.y,  LOG2E * b1v.z,  LOG2E * b1v.w};
        f4v bmf0  = {LOG2E * bm0v.x, LOG2E * bm0v.y, LOG2E * bm0v.z, LOG2E * bm0v.w};
        f4v bmf1  = {LOG2E * bm1v.x, LOG2E * bm1v.y, LOG2E * bm1v.z, LOG2E * bm1v.w};
        f4v bfin  = {0.f, 0.f, 0.f, 0.f};
        bfin[0] = ((q & 1) == 0) ? bf[gq] : 0.0f;   // rows 0 (g0) and 8 (g1)

        // --- idx frags: byte offsets t*B_*4 ---
        int4 id0 = *(const int4*)(tf_idx + g0 * K_ + 4 * q);
        int4 id1 = *(const int4*)(tf_idx + g1 * K_ + 4 * q);
        id0.x <<= 10; id0.y <<= 10; id0.z <<= 10; id0.w <<= 10;
        id1.x <<= 10; id1.y <<= 10; id1.z <<= 10; id1.w <<= 10;

        #pragma unroll
        for (int t = 0; t < 4; ++t) {
            const int bb = bq * 64 + t * 16;
            const int vb = (bb + col) * 4;

            float x0 = *(const float*)(fc + id0.x + vb);
            float x1 = *(const float*)(fc + id0.y + vb);
            float x2 = *(const float*)(fc + id0.z + vb);
            float x3 = *(const float*)(fc + id0.w + vb);
            float y0 = *(const float*)(fc + id1.x + vb);
            float y1 = *(const float*)(fc + id1.y + vb);
            float y2 = *(const float*)(fc + id1.z + vb);
            float y3 = *(const float*)(fc + id1.w + vb);
            uint2 bg0, bg1;
            bg0.x = cvtpk_u(x0, x1); bg0.y = cvtpk_u(x2, x3);
            bg1.x = cvtpk_u(y0, y1); bg1.y = cvtpk_u(y2, y3);

            f4v acc = mfma16(A1g0, bg0, bias1);
            acc     = mfma16(A1g1, bg1, acc);

            uint2 bh;
            bh.x = cvtpk_u(selu_u(acc[0]), selu_u(acc[1]));
            bh.y = cvtpk_u(selu_u(acc[2]), selu_u(acc[3]));

            acc  = mfma16(AM0, bh, bmf0);
            bh.x = cvtpk_u(selu_u(acc[0]), selu_u(acc[1]));
            bh.y = cvtpk_u(selu_u(acc[2]), selu_u(acc[3]));

            acc  = mfma16(AM1, bh, bmf1);
            bh.x = cvtpk_u(selu_u(acc[0]), selu_u(acc[1]));
            bh.y = cvtpk_u(selu_u(acc[2]), selu_u(acc[3]));

            acc = mfma16(AF, bh, bfin);

            // D row0 (g even) in lanes q==0, row8 (g odd) in q==2
            if (!(q & 1))
                smem[t * 16 + col][2 * pp + ((q >> 1) & 1)] = acc[0];
        }
    }

    __syncthreads();

    // epilogue: 8 threads per batch row, float2 each -> full 64B lines
    {
        const int row = tid >> 3;           // 0..63 (local batch row)
        const int seg = tid & 7;            // 8B segment within the line
        float2 v = make_float2(smem[row][seg * 2 + 0], smem[row][seg * 2 + 1]);
        *(float2*)(out + (long)(bq * 64 + row) * G_ + gc * 16 + seg * 2) = v;
    }
}

// ---------- fallback (no workspace): direct scalar path ----------
#define FGPB 4
__device__ __forceinline__ float selu_f(float x) {
    const float scale = 1.0507009873554805f;
    const float sa    = 1.7580993408473766f;
    float e   = __expf(x);
    float neg = fmaf(sa, e, -sa);
    return x > 0.0f ? scale * x : neg;
}
template<bool TRANSPOSED>
__global__ __launch_bounds__(256) void decoder_kernel(
    const float* __restrict__ featsrc, const int* __restrict__ tf_idx,
    const float* __restrict__ W1, const float* __restrict__ b1,
    const float* __restrict__ Wm, const float* __restrict__ bm,
    const float* __restrict__ Wf, const float* __restrict__ bf,
    float* __restrict__ out)
{
    const int b  = threadIdx.x;
    const int g0 = blockIdx.x * FGPB;
    float res[FGPB];
    #pragma unroll
    for (int gi = 0; gi < FGPB; ++gi) {
        const int g = g0 + gi;
        float xg[K_];
        #pragma unroll
        for (int k = 0; k < K_; ++k) {
            int t = tf_idx[g * K_ + k];
            xg[k] = TRANSPOSED ? featsrc[t * B_ + b] : featsrc[b * T_ + t];
        }
        float h[W_];
        #pragma unroll
        for (int w = 0; w < W_; ++w) {
            float acc = b1[g * W_ + w];
            #pragma unroll
            for (int k = 0; k < K_; ++k)
                acc = fmaf(xg[k], W1[(g * W_ + w) * K_ + k], acc);
            h[w] = selu_f(acc);
        }
        #pragma unroll
        for (int d = 0; d < D_; ++d) {
            const float* wmd = Wm + ((size_t)d * G_ + g) * (W_ * W_);
            const float* bmd = bm + ((size_t)d * G_ + g) * W_;
            float h2[W_];
            #pragma unroll
            for (int v = 0; v < W_; ++v) {
                float acc = bmd[v];
                #pragma unroll
                for (int w = 0; w < W_; ++w)
                    acc = fmaf(h[w], wmd[v * W_ + w], acc);
                h2[v] = selu_f(acc);
            }
            #pragma unroll
            for (int w = 0; w < W_; ++w) h[w] = h2[w];
        }
        float acc = bf[g];
        #pragma unroll
        for (int w = 0; w < W_; ++w)
            acc = fmaf(h[w], Wf[g * W_ + w], acc);
        res[gi] = acc;
    }
    float4* o = (float4*)(out + (size_t)b * G_ + g0);
    o[0] = make_float4(res[0], res[1], res[2], res[3]);
}

extern "C" void kernel_launch(void* const* d_in, const int* in_sizes, int n_in,
                              void* d_out, int out_size, void* d_ws, size_t ws_size,
                              hipStream_t stream) {
    const float* feat   = (const float*)d_in[0];
    const int*   tf_idx = (const int*)  d_in[1];
    const float* W1     = (const float*)d_in[2];
    const float* b1     = (const float*)d_in[3];
    const float* Wm     = (const float*)d_in[4];
    const float* bm     = (const float*)d_in[5];
    const float* Wf     = (const float*)d_in[6];
    const float* bf     = (const float*)d_in[7];
    float* out = (float*)d_out;

    const size_t featT_b = (size_t)T_ * B_ * sizeof(float);   // 1.536 MB

    if (ws_size >= featT_b) {
        float* featT = (float*)d_ws;
        hipLaunchKernelGGL(transpose_feat, dim3((T_ + 31) / 32, B_ / 32),
                           dim3(32, 8), 0, stream, feat, featT);
        hipLaunchKernelGGL(decoder_mfma, dim3(B_ / 64, G_ / 16), dim3(512), 0,
                           stream, featT, tf_idx, W1, b1, Wm, bm, Wf, bf, out);
    } else {
        hipLaunchKernelGGL((decoder_kernel<false>), dim3(G_ / FGPB), dim3(B_), 0,
                           stream, feat, tf_idx, W1, b1, Wm, bm, Wf, bf, out);
    }
}

// Round 17
// 49.155 us; speedup vs baseline: 1.3062x; 1.0824x over previous
//
#include <hip/hip_runtime.h>
#include <hip/hip_fp16.h>

#define G_ 20000
#define W_ 8
#define K_ 16
#define T_ 1500
#define B_ 256
#define D_ 2

using h4  = __attribute__((ext_vector_type(4))) __fp16;
using f4v = __attribute__((ext_vector_type(4))) float;
typedef decltype(__builtin_amdgcn_cvt_pkrtz(0.0f, 0.0f)) v2h;

// ---------- prep: feat (B,T) -> featT (T,B) ----------
__global__ void transpose_feat(const float* __restrict__ feat,
                               float* __restrict__ featT) {
    __shared__ float tile[32][33];
    int t0 = blockIdx.x * 32;
    int b0 = blockIdx.y * 32;
    int tx = threadIdx.x, ty = threadIdx.y;  // block (32,8)
    #pragma unroll
    for (int i = 0; i < 32; i += 8) {
        int bb = b0 + ty + i, tt = t0 + tx;
        if (tt < T_) tile[ty + i][tx] = feat[bb * T_ + tt];
    }
    __syncthreads();
    #pragma unroll
    for (int i = 0; i < 32; i += 8) {
        int tt = t0 + ty + i, bb = b0 + tx;
        if (tt < T_) featT[tt * B_ + bb] = tile[tx][ty + i];
    }
}

// ---------- main MFMA kernel ----------

__device__ __forceinline__ float selu_u(float u) {
    const float ALPHA = 1.6732632423543772f;
    const float LN2   = 0.6931471805599453f;
    float e = __builtin_amdgcn_exp2f(u);
    float m = fmaf(ALPHA, e, -ALPHA);
    return fmaf(fmaxf(u, 0.0f), LN2, fminf(m, 0.0f));
}

__device__ __forceinline__ unsigned cvtpk_u(float a, float b) {
    v2h t = __builtin_amdgcn_cvt_pkrtz(a, b);
    unsigned u; __builtin_memcpy(&u, &t, 4);
    return u;
}

__device__ __forceinline__ f4v mfma16(uint2 a, uint2 b, f4v c) {
    h4 ah, bh;
    __builtin_memcpy(&ah, &a, 8);
    __builtin_memcpy(&bh, &b, 8);
    return __builtin_amdgcn_mfma_f32_16x16x16f16(ah, bh, c, 0, 0, 0);
}

// Grid (B/64, G/16) = (4,1250), block = 512 threads = 8 waves, 1 pair/wave.
// r16 lesson: occupancy (35/51/71%) does NOT move dur — the kernel is
// per-wave-dependency-bound. r16's __launch_bounds__(512,8) squeezed the
// wave to 32 VGPRs, forcing the 4 independent batch-tile chains to run
// serially. Fix: (512,4) -> 128-VGPR budget, and hoist ALL 32 gathers
// into registers up front so the compiler interleaves the 4 chains'
// mfma/selu streams (ILP covers each chain's latency).
__global__ __launch_bounds__(512, 4) void decoder_mfma(
    const float* __restrict__ featT,    // (T,B)
    const int*   __restrict__ tf_idx,   // (G,K)
    const float* __restrict__ W1,       // (G,W,K)
    const float* __restrict__ b1,       // (G,W)
    const float* __restrict__ Wm,       // (D,G,W,W)
    const float* __restrict__ bm,       // (D,G,W)
    const float* __restrict__ Wf,       // (G,W)
    const float* __restrict__ bf,       // (G,)
    float* __restrict__ out)            // (B,G)
{
    const float LOG2E = 1.44269504088896340736f;
    const float SCALE = 1.0507009873554805f;
    const float SL    = SCALE * LOG2E;

    const int tid  = threadIdx.x;
    const int lane = tid & 63;
    const int wv   = tid >> 6;              // 0..7 = pair within chunk
    const int bq   = blockIdx.x;             // batch quarter (64 rows)
    const int gc   = blockIdx.y;             // group-chunk of 16
    const char* fc = (const char*)featT;

    const int col   = lane & 15;             // A-row / B-col / C-col
    const int q     = lane >> 4;             // k/row quad
    const bool rlt8 = col < 8;
    const int kq    = (q & 1) * 4;           // k-offset within an 8-wide row

    __shared__ float smem[64][17];

    {
        const int pp = wv;
        const int p  = gc * 8 + pp;
        const int g0 = 2 * p, g1 = 2 * p + 1;
        const int ga = rlt8 ? g0 : g1;       // row-side group (A-row = col)
        const int ra = rlt8 ? col : col - 8;
        const int gq = (q < 2) ? g0 : g1;    // row-quad-side group (C rows)

        // --- idx frags first so gathers can issue earliest ---
        int4 id0 = *(const int4*)(tf_idx + g0 * K_ + 4 * q);
        int4 id1 = *(const int4*)(tf_idx + g1 * K_ + 4 * q);
        id0.x <<= 10; id0.y <<= 10; id0.z <<= 10; id0.w <<= 10;
        id1.x <<= 10; id1.y <<= 10; id1.z <<= 10; id1.w <<= 10;

        // --- hoisted gathers: ALL 4 chains' inputs in flight at once ---
        float xv[4][8];
        #pragma unroll
        for (int t = 0; t < 4; ++t) {
            const unsigned vb = (unsigned)((bq * 64 + t * 16 + col) * 4);
            xv[t][0] = *(const float*)(fc + (unsigned)id0.x + vb);
            xv[t][1] = *(const float*)(fc + (unsigned)id0.y + vb);
            xv[t][2] = *(const float*)(fc + (unsigned)id0.z + vb);
            xv[t][3] = *(const float*)(fc + (unsigned)id0.w + vb);
            xv[t][4] = *(const float*)(fc + (unsigned)id1.x + vb);
            xv[t][5] = *(const float*)(fc + (unsigned)id1.y + vb);
            xv[t][6] = *(const float*)(fc + (unsigned)id1.z + vb);
            xv[t][7] = *(const float*)(fc + (unsigned)id1.w + vb);
        }

        // --- A1: rows0-7 = LOG2E*W1_g0[w][k], rows8-15 = g1; split halves ---
        float4 w1v = *(const float4*)(W1 + ((long)ga * W_ + ra) * K_ + 4 * q);
        uint2 af;
        af.x = cvtpk_u(LOG2E * w1v.x, LOG2E * w1v.y);
        af.y = cvtpk_u(LOG2E * w1v.z, LOG2E * w1v.w);
        uint2 A1g0, A1g1;
        A1g0.x = rlt8 ? af.x : 0u;  A1g0.y = rlt8 ? af.y : 0u;
        A1g1.x = rlt8 ? 0u : af.x;  A1g1.y = rlt8 ? 0u : af.y;

        // --- AM0/AM1 block-diag: nonzero iff (col<8)==(q<2) ---
        const bool diag = (rlt8 == (q < 2));
        float4 wm0v = *(const float4*)(Wm + ((long)0 * G_ + ga) * 64 + ra * 8 + kq);
        float4 wm1v = *(const float4*)(Wm + ((long)1 * G_ + ga) * 64 + ra * 8 + kq);
        uint2 AM0, AM1;
        AM0.x = diag ? cvtpk_u(SL * wm0v.x, SL * wm0v.y) : 0u;
        AM0.y = diag ? cvtpk_u(SL * wm0v.z, SL * wm0v.w) : 0u;
        AM1.x = diag ? cvtpk_u(SL * wm1v.x, SL * wm1v.y) : 0u;
        AM1.y = diag ? cvtpk_u(SL * wm1v.z, SL * wm1v.w) : 0u;

        // --- AF: row0 = SCALE*Wf_g0 (k0-7); row8 = SCALE*Wf_g1 (k8-15) ---
        const bool fnz = (ra == 0) && diag;
        float4 wfv = *(const float4*)(Wf + (long)ga * W_ + kq);
        uint2 AF;
        AF.x = fnz ? cvtpk_u(SCALE * wfv.x, SCALE * wfv.y) : 0u;
        AF.y = fnz ? cvtpk_u(SCALE * wfv.z, SCALE * wfv.w) : 0u;

        // --- bias C-in frags (rows 4q..4q+3) ---
        float4 b1v  = *(const float4*)(b1 + (long)gq * W_ + kq);
        float4 bm0v = *(const float4*)(bm + ((long)0 * G_ + gq) * W_ + kq);
        float4 bm1v = *(const float4*)(bm + ((long)1 * G_ + gq) * W_ + kq);
        f4v bias1 = {LOG2E * b1v.x,  LOG2E * b1v.y,  LOG2E * b1v.z,  LOG2E * b1v.w};
        f4v bmf0  = {LOG2E * bm0v.x, LOG2E * bm0v.y, LOG2E * bm0v.z, LOG2E * bm0v.w};
        f4v bmf1  = {LOG2E * bm1v.x, LOG2E * bm1v.y, LOG2E * bm1v.z, LOG2E * bm1v.w};
        f4v bfin  = {0.f, 0.f, 0.f, 0.f};
        bfin[0] = ((q & 1) == 0) ? bf[gq] : 0.0f;   // rows 0 (g0) and 8 (g1)

        // --- 4 register-disjoint chains: compiler interleaves for ILP ---
        #pragma unroll
        for (int t = 0; t < 4; ++t) {
            uint2 bg0, bg1;
            bg0.x = cvtpk_u(xv[t][0], xv[t][1]); bg0.y = cvtpk_u(xv[t][2], xv[t][3]);
            bg1.x = cvtpk_u(xv[t][4], xv[t][5]); bg1.y = cvtpk_u(xv[t][6], xv[t][7]);

            f4v acc = mfma16(A1g0, bg0, bias1);
            acc     = mfma16(A1g1, bg1, acc);

            uint2 bh;
            bh.x = cvtpk_u(selu_u(acc[0]), selu_u(acc[1]));
            bh.y = cvtpk_u(selu_u(acc[2]), selu_u(acc[3]));

            acc  = mfma16(AM0, bh, bmf0);
            bh.x = cvtpk_u(selu_u(acc[0]), selu_u(acc[1]));
            bh.y = cvtpk_u(selu_u(acc[2]), selu_u(acc[3]));

            acc  = mfma16(AM1, bh, bmf1);
            bh.x = cvtpk_u(selu_u(acc[0]), selu_u(acc[1]));
            bh.y = cvtpk_u(selu_u(acc[2]), selu_u(acc[3]));

            acc = mfma16(AF, bh, bfin);

            // D row0 (g even) in lanes q==0, row8 (g odd) in q==2
            if (!(q & 1))
                smem[t * 16 + col][2 * pp + ((q >> 1) & 1)] = acc[0];
        }
    }

    __syncthreads();

    // epilogue: 8 threads per batch row, float2 each -> full 64B lines
    {
        const int row = tid >> 3;           // 0..63 (local batch row)
        const int seg = tid & 7;            // 8B segment within the line
        float2 v = make_float2(smem[row][seg * 2 + 0], smem[row][seg * 2 + 1]);
        *(float2*)(out + (long)(bq * 64 + row) * G_ + gc * 16 + seg * 2) = v;
    }
}

// ---------- fallback (no workspace): direct scalar path ----------
#define FGPB 4
__device__ __forceinline__ float selu_f(float x) {
    const float scale = 1.0507009873554805f;
    const float sa    = 1.7580993408473766f;
    float e   = __expf(x);
    float neg = fmaf(sa, e, -sa);
    return x > 0.0f ? scale * x : neg;
}
template<bool TRANSPOSED>
__global__ __launch_bounds__(256) void decoder_kernel(
    const float* __restrict__ featsrc, const int* __restrict__ tf_idx,
    const float* __restrict__ W1, const float* __restrict__ b1,
    const float* __restrict__ Wm, const float* __restrict__ bm,
    const float* __restrict__ Wf, const float* __restrict__ bf,
    float* __restrict__ out)
{
    const int b  = threadIdx.x;
    const int g0 = blockIdx.x * FGPB;
    float res[FGPB];
    #pragma unroll
    for (int gi = 0; gi < FGPB; ++gi) {
        const int g = g0 + gi;
        float xg[K_];
        #pragma unroll
        for (int k = 0; k < K_; ++k) {
            int t = tf_idx[g * K_ + k];
            xg[k] = TRANSPOSED ? featsrc[t * B_ + b] : featsrc[b * T_ + t];
        }
        float h[W_];
        #pragma unroll
        for (int w = 0; w < W_; ++w) {
            float acc = b1[g * W_ + w];
            #pragma unroll
            for (int k = 0; k < K_; ++k)
                acc = fmaf(xg[k], W1[(g * W_ + w) * K_ + k], acc);
            h[w] = selu_f(acc);
        }
        #pragma unroll
        for (int d = 0; d < D_; ++d) {
            const float* wmd = Wm + ((size_t)d * G_ + g) * (W_ * W_);
            const float* bmd = bm + ((size_t)d * G_ + g) * W_;
            float h2[W_];
            #pragma unroll
            for (int v = 0; v < W_; ++v) {
                float acc = bmd[v];
                #pragma unroll
                for (int w = 0; w < W_; ++w)
                    acc = fmaf(h[w], wmd[v * W_ + w], acc);
                h2[v] = selu_f(acc);
            }
            #pragma unroll
            for (int w = 0; w < W_; ++w) h[w] = h2[w];
        }
        float acc = bf[g];
        #pragma unroll
        for (int w = 0; w < W_; ++w)
            acc = fmaf(h[w], Wf[g * W_ + w], acc);
        res[gi] = acc;
    }
    float4* o = (float4*)(out + (size_t)b * G_ + g0);
    o[0] = make_float4(res[0], res[1], res[2], res[3]);
}

extern "C" void kernel_launch(void* const* d_in, const int* in_sizes, int n_in,
                              void* d_out, int out_size, void* d_ws, size_t ws_size,
                              hipStream_t stream) {
    const float* feat   = (const float*)d_in[0];
    const int*   tf_idx = (const int*)  d_in[1];
    const float* W1     = (const float*)d_in[2];
    const float* b1     = (const float*)d_in[3];
    const float* Wm     = (const float*)d_in[4];
    const float* bm     = (const float*)d_in[5];
    const float* Wf     = (const float*)d_in[6];
    const float* bf     = (const float*)d_in[7];
    float* out = (float*)d_out;

    const size_t featT_b = (size_t)T_ * B_ * sizeof(float);   // 1.536 MB

    if (ws_size >= featT_b) {
        float* featT = (float*)d_ws;
        hipLaunchKernelGGL(transpose_feat, dim3((T_ + 31) / 32, B_ / 32),
                           dim3(32, 8), 0, stream, feat, featT);
        hipLaunchKernelGGL(decoder_mfma, dim3(B_ / 64, G_ / 16), dim3(512), 0,
                           stream, featT, tf_idx, W1, b1, Wm, bm, Wf, bf, out);
    } else {
        hipLaunchKernelGGL((decoder_kernel<false>), dim3(G_ / FGPB), dim3(B_), 0,
                           stream, feat, tf_idx, W1, b1, Wm, bm, Wf, bf, out);
    }
}

// Round 19
// 46.649 us; speedup vs baseline: 1.3763x; 1.0537x over previous
//
#include <hip/hip_runtime.h>
#include <hip/hip_fp16.h>

#define G_ 20000
#define W_ 8
#define K_ 16
#define T_ 1500
#define B_ 256
#define D_ 2

using h4  = __attribute__((ext_vector_type(4))) __fp16;
using f4v = __attribute__((ext_vector_type(4))) float;
typedef decltype(__builtin_amdgcn_cvt_pkrtz(0.0f, 0.0f)) v2h;  // __fp16 x2

// ---------- prep: feat (B,T) -> featT (T,B) ----------
__global__ void transpose_feat(const float* __restrict__ feat,
                               float* __restrict__ featT) {
    __shared__ float tile[32][33];
    int t0 = blockIdx.x * 32;
    int b0 = blockIdx.y * 32;
    int tx = threadIdx.x, ty = threadIdx.y;  // block (32,8)
    #pragma unroll
    for (int i = 0; i < 32; i += 8) {
        int bb = b0 + ty + i, tt = t0 + tx;
        if (tt < T_) tile[ty + i][tx] = feat[bb * T_ + tt];
    }
    __syncthreads();
    #pragma unroll
    for (int i = 0; i < 32; i += 8) {
        int tt = t0 + ty + i, bb = b0 + tx;
        if (tt < T_) featT[tt * B_ + bb] = tile[tx][ty + i];
    }
}

// ---------- main MFMA kernel ----------

__device__ __forceinline__ unsigned cvtpk_u(float a, float b) {
    v2h t = __builtin_amdgcn_cvt_pkrtz(a, b);
    unsigned u; __builtin_memcpy(&u, &t, 4);
    return u;
}
__device__ __forceinline__ unsigned u_from_v2h(v2h h) {
    unsigned u; __builtin_memcpy(&u, &h, 4); return u;
}

// SELU on a 4-f32 mfma accumulator quad -> packed f16 pair (next B frag).
// exp2 in f32 (4 trans ops); affine/min/max tail in packed f16 vectors
// (v_pk_fma_f16 / v_pk_min_f16 / v_pk_max_f16 via clang vector ops +
// __builtin_elementwise_min/max — r18's __hmin2/__hmax2 don't exist in
// ROCm 7.2 headers). 12 inst/quad vs 22 scalar-f32; result IS the packed
// next-layer B fragment. Overflow-safe: u>16 -> he=inf -> m=+inf, but
// min(m,0) clips (that branch only matters for u<=0 where e<=1).
__device__ __forceinline__ uint2 selu_quad(f4v acc) {
    const v2h A2  = {(__fp16)( 1.6732632423543772f), (__fp16)( 1.6732632423543772f)};
    const v2h nA2 = {(__fp16)(-1.6732632423543772f), (__fp16)(-1.6732632423543772f)};
    const v2h L2h = {(__fp16)( 0.6931471805599453f), (__fp16)( 0.6931471805599453f)};
    const v2h Z2  = {(__fp16)0.0f, (__fp16)0.0f};
    float e0 = __builtin_amdgcn_exp2f(acc[0]);
    float e1 = __builtin_amdgcn_exp2f(acc[1]);
    float e2 = __builtin_amdgcn_exp2f(acc[2]);
    float e3 = __builtin_amdgcn_exp2f(acc[3]);
    v2h hu01 = __builtin_amdgcn_cvt_pkrtz(acc[0], acc[1]);
    v2h hu23 = __builtin_amdgcn_cvt_pkrtz(acc[2], acc[3]);
    v2h he01 = __builtin_amdgcn_cvt_pkrtz(e0, e1);
    v2h he23 = __builtin_amdgcn_cvt_pkrtz(e2, e3);
    v2h m01 = __builtin_elementwise_min(he01 * A2 + nA2, Z2);
    v2h m23 = __builtin_elementwise_min(he23 * A2 + nA2, Z2);
    v2h r01 = __builtin_elementwise_max(hu01, Z2) * L2h + m01;
    v2h r23 = __builtin_elementwise_max(hu23, Z2) * L2h + m23;
    return make_uint2(u_from_v2h(r01), u_from_v2h(r23));
}

__device__ __forceinline__ f4v mfma16(uint2 a, uint2 b, f4v c) {
    h4 ah, bh;
    __builtin_memcpy(&ah, &a, 8);
    __builtin_memcpy(&bh, &b, 8);
    return __builtin_amdgcn_mfma_f32_16x16x16f16(ah, bh, c, 0, 0, 0);
}

// Grid (B/64, G/16) = (4,1250), block = 512 threads = 8 waves, 1 pair/wave.
// r13-r17 lesson: occupancy knobs don't move dur — VALU/trans issue-bound.
// This round deletes instructions: packed-f16 selu tail (−~90/wave) and
// immediate-offset gathers (8 base addrs once, +64B steps fold into the
// global_load imm) (−~24/wave).
__global__ __launch_bounds__(512, 4) void decoder_mfma(
    const float* __restrict__ featT,    // (T,B)
    const int*   __restrict__ tf_idx,   // (G,K)
    const float* __restrict__ W1,       // (G,W,K)
    const float* __restrict__ b1,       // (G,W)
    const float* __restrict__ Wm,       // (D,G,W,W)
    const float* __restrict__ bm,       // (D,G,W)
    const float* __restrict__ Wf,       // (G,W)
    const float* __restrict__ bf,       // (G,)
    float* __restrict__ out)            // (B,G)
{
    const float LOG2E = 1.44269504088896340736f;
    const float SCALE = 1.0507009873554805f;
    const float SL    = SCALE * LOG2E;

    const int tid  = threadIdx.x;
    const int lane = tid & 63;
    const int wv   = tid >> 6;              // 0..7 = pair within chunk
    const int bq   = blockIdx.x;             // batch quarter (64 rows)
    const int gc   = blockIdx.y;             // group-chunk of 16
    const char* fc = (const char*)featT;

    const int col   = lane & 15;             // A-row / B-col / C-col
    const int q     = lane >> 4;             // k/row quad
    const bool rlt8 = col < 8;
    const int kq    = (q & 1) * 4;           // k-offset within an 8-wide row

    __shared__ float smem[64][17];

    {
        const int pp = wv;
        const int p  = gc * 8 + pp;
        const int g0 = 2 * p, g1 = 2 * p + 1;
        const int ga = rlt8 ? g0 : g1;       // row-side group (A-row = col)
        const int ra = rlt8 ? col : col - 8;
        const int gq = (q < 2) ? g0 : g1;    // row-quad-side group (C rows)

        // --- gather bases: 8 addrs once; t-steps are imm offsets ---
        int4 id0 = *(const int4*)(tf_idx + g0 * K_ + 4 * q);
        int4 id1 = *(const int4*)(tf_idx + g1 * K_ + 4 * q);
        const unsigned vb0 = (unsigned)((bq * 64 + col) * 4);
        const char* p0 = fc + (((unsigned)id0.x << 10) + vb0);
        const char* p1 = fc + (((unsigned)id0.y << 10) + vb0);
        const char* p2 = fc + (((unsigned)id0.z << 10) + vb0);
        const char* p3 = fc + (((unsigned)id0.w << 10) + vb0);
        const char* p4 = fc + (((unsigned)id1.x << 10) + vb0);
        const char* p5 = fc + (((unsigned)id1.y << 10) + vb0);
        const char* p6 = fc + (((unsigned)id1.z << 10) + vb0);
        const char* p7 = fc + (((unsigned)id1.w << 10) + vb0);

        float xv[4][8];
        #pragma unroll
        for (int t = 0; t < 4; ++t) {
            xv[t][0] = *(const float*)(p0 + t * 64);
            xv[t][1] = *(const float*)(p1 + t * 64);
            xv[t][2] = *(const float*)(p2 + t * 64);
            xv[t][3] = *(const float*)(p3 + t * 64);
            xv[t][4] = *(const float*)(p4 + t * 64);
            xv[t][5] = *(const float*)(p5 + t * 64);
            xv[t][6] = *(const float*)(p6 + t * 64);
            xv[t][7] = *(const float*)(p7 + t * 64);
        }

        // --- A1: rows0-7 = LOG2E*W1_g0[w][k], rows8-15 = g1; split halves ---
        float4 w1v = *(const float4*)(W1 + ((long)ga * W_ + ra) * K_ + 4 * q);
        uint2 af;
        af.x = cvtpk_u(LOG2E * w1v.x, LOG2E * w1v.y);
        af.y = cvtpk_u(LOG2E * w1v.z, LOG2E * w1v.w);
        uint2 A1g0, A1g1;
        A1g0.x = rlt8 ? af.x : 0u;  A1g0.y = rlt8 ? af.y : 0u;
        A1g1.x = rlt8 ? 0u : af.x;  A1g1.y = rlt8 ? 0u : af.y;

        // --- AM0/AM1 block-diag: nonzero iff (col<8)==(q<2) ---
        const bool diag = (rlt8 == (q < 2));
        float4 wm0v = *(const float4*)(Wm + ((long)0 * G_ + ga) * 64 + ra * 8 + kq);
        float4 wm1v = *(const float4*)(Wm + ((long)1 * G_ + ga) * 64 + ra * 8 + kq);
        uint2 AM0, AM1;
        AM0.x = diag ? cvtpk_u(SL * wm0v.x, SL * wm0v.y) : 0u;
        AM0.y = diag ? cvtpk_u(SL * wm0v.z, SL * wm0v.w) : 0u;
        AM1.x = diag ? cvtpk_u(SL * wm1v.x, SL * wm1v.y) : 0u;
        AM1.y = diag ? cvtpk_u(SL * wm1v.z, SL * wm1v.w) : 0u;

        // --- AF: row0 = SCALE*Wf_g0 (k0-7); row8 = SCALE*Wf_g1 (k8-15) ---
        const bool fnz = (ra == 0) && diag;
        float4 wfv = *(const float4*)(Wf + (long)ga * W_ + kq);
        uint2 AF;
        AF.x = fnz ? cvtpk_u(SCALE * wfv.x, SCALE * wfv.y) : 0u;
        AF.y = fnz ? cvtpk_u(SCALE * wfv.z, SCALE * wfv.w) : 0u;

        // --- bias C-in frags (rows 4q..4q+3) ---
        float4 b1v  = *(const float4*)(b1 + (long)gq * W_ + kq);
        float4 bm0v = *(const float4*)(bm + ((long)0 * G_ + gq) * W_ + kq);
        float4 bm1v = *(const float4*)(bm + ((long)1 * G_ + gq) * W_ + kq);
        f4v bias1 = {LOG2E * b1v.x,  LOG2E * b1v.y,  LOG2E * b1v.z,  LOG2E * b1v.w};
        f4v bmf0  = {LOG2E * bm0v.x, LOG2E * bm0v.y, LOG2E * bm0v.z, LOG2E * bm0v.w};
        f4v bmf1  = {LOG2E * bm1v.x, LOG2E * bm1v.y, LOG2E * bm1v.z, LOG2E * bm1v.w};
        f4v bfin  = {0.f, 0.f, 0.f, 0.f};
        bfin[0] = ((q & 1) == 0) ? bf[gq] : 0.0f;   // rows 0 (g0) and 8 (g1)

        // --- 4 register-disjoint chains: compiler interleaves for ILP ---
        #pragma unroll
        for (int t = 0; t < 4; ++t) {
            uint2 bg0, bg1;
            bg0.x = cvtpk_u(xv[t][0], xv[t][1]); bg0.y = cvtpk_u(xv[t][2], xv[t][3]);
            bg1.x = cvtpk_u(xv[t][4], xv[t][5]); bg1.y = cvtpk_u(xv[t][6], xv[t][7]);

            f4v acc = mfma16(A1g0, bg0, bias1);
            acc     = mfma16(A1g1, bg1, acc);

            uint2 bh = selu_quad(acc);
            acc = mfma16(AM0, bh, bmf0);
            bh  = selu_quad(acc);
            acc = mfma16(AM1, bh, bmf1);
            bh  = selu_quad(acc);
            acc = mfma16(AF, bh, bfin);

            // D row0 (g even) in lanes q==0, row8 (g odd) in q==2
            if (!(q & 1))
                smem[t * 16 + col][2 * pp + ((q >> 1) & 1)] = acc[0];
        }
    }

    __syncthreads();

    // epilogue: 8 threads per batch row, float2 each -> full 64B lines
    {
        const int row = tid >> 3;           // 0..63 (local batch row)
        const int seg = tid & 7;            // 8B segment within the line
        float2 v = make_float2(smem[row][seg * 2 + 0], smem[row][seg * 2 + 1]);
        *(float2*)(out + (long)(bq * 64 + row) * G_ + gc * 16 + seg * 2) = v;
    }
}

// ---------- fallback (no workspace): direct scalar path ----------
#define FGPB 4
__device__ __forceinline__ float selu_f(float x) {
    const float scale = 1.0507009873554805f;
    const float sa    = 1.7580993408473766f;
    float e   = __expf(x);
    float neg = fmaf(sa, e, -sa);
    return x > 0.0f ? scale * x : neg;
}
template<bool TRANSPOSED>
__global__ __launch_bounds__(256) void decoder_kernel(
    const float* __restrict__ featsrc, const int* __restrict__ tf_idx,
    const float* __restrict__ W1, const float* __restrict__ b1,
    const float* __restrict__ Wm, const float* __restrict__ bm,
    const float* __restrict__ Wf, const float* __restrict__ bf,
    float* __restrict__ out)
{
    const int b  = threadIdx.x;
    const int g0 = blockIdx.x * FGPB;
    float res[FGPB];
    #pragma unroll
    for (int gi = 0; gi < FGPB; ++gi) {
        const int g = g0 + gi;
        float xg[K_];
        #pragma unroll
        for (int k = 0; k < K_; ++k) {
            int t = tf_idx[g * K_ + k];
            xg[k] = TRANSPOSED ? featsrc[t * B_ + b] : featsrc[b * T_ + t];
        }
        float h[W_];
        #pragma unroll
        for (int w = 0; w < W_; ++w) {
            float acc = b1[g * W_ + w];
            #pragma unroll
            for (int k = 0; k < K_; ++k)
                acc = fmaf(xg[k], W1[(g * W_ + w) * K_ + k], acc);
            h[w] = selu_f(acc);
        }
        #pragma unroll
        for (int d = 0; d < D_; ++d) {
            const float* wmd = Wm + ((size_t)d * G_ + g) * (W_ * W_);
            const float* bmd = bm + ((size_t)d * G_ + g) * W_;
            float h2[W_];
            #pragma unroll
            for (int v = 0; v < W_; ++v) {
                float acc = bmd[v];
                #pragma unroll
                for (int w = 0; w < W_; ++w)
                    acc = fmaf(h[w], wmd[v * W_ + w], acc);
                h2[v] = selu_f(acc);
            }
            #pragma unroll
            for (int w = 0; w < W_; ++w) h[w] = h2[w];
        }
        float acc = bf[g];
        #pragma unroll
        for (int w = 0; w < W_; ++w)
            acc = fmaf(h[w], Wf[g * W_ + w], acc);
        res[gi] = acc;
    }
    float4* o = (float4*)(out + (size_t)b * G_ + g0);
    o[0] = make_float4(res[0], res[1], res[2], res[3]);
}

extern "C" void kernel_launch(void* const* d_in, const int* in_sizes, int n_in,
                              void* d_out, int out_size, void* d_ws, size_t ws_size,
                              hipStream_t stream) {
    const float* feat   = (const float*)d_in[0];
    const int*   tf_idx = (const int*)  d_in[1];
    const float* W1     = (const float*)d_in[2];
    const float* b1     = (const float*)d_in[3];
    const float* Wm     = (const float*)d_in[4];
    const float* bm     = (const float*)d_in[5];
    const float* Wf     = (const float*)d_in[6];
    const float* bf     = (const float*)d_in[7];
    float* out = (float*)d_out;

    const size_t featT_b = (size_t)T_ * B_ * sizeof(float);   // 1.536 MB

    if (ws_size >= featT_b) {
        float* featT = (float*)d_ws;
        hipLaunchKernelGGL(transpose_feat, dim3((T_ + 31) / 32, B_ / 32),
                           dim3(32, 8), 0, stream, feat, featT);
        hipLaunchKernelGGL(decoder_mfma, dim3(B_ / 64, G_ / 16), dim3(512), 0,
                           stream, featT, tf_idx, W1, b1, Wm, bm, Wf, bf, out);
    } else {
        hipLaunchKernelGGL((decoder_kernel<false>), dim3(G_ / FGPB), dim3(B_), 0,
                           stream, feat, tf_idx, W1, b1, Wm, bm, Wf, bf, out);
    }
}

// Round 20
// 46.102 us; speedup vs baseline: 1.3927x; 1.0119x over previous
//
#include <hip/hip_runtime.h>
#include <hip/hip_fp16.h>

#define G_ 20000
#define W_ 8
#define K_ 16
#define T_ 1500
#define B_ 256
#define D_ 2

using h4  = __attribute__((ext_vector_type(4))) __fp16;
using f4v = __attribute__((ext_vector_type(4))) float;
typedef decltype(__builtin_amdgcn_cvt_pkrtz(0.0f, 0.0f)) v2h;  // __fp16 x2

// ---------- prep: feat (B,T) -> featT (T,B) ----------
__global__ void transpose_feat(const float* __restrict__ feat,
                               float* __restrict__ featT) {
    __shared__ float tile[32][33];
    int t0 = blockIdx.x * 32;
    int b0 = blockIdx.y * 32;
    int tx = threadIdx.x, ty = threadIdx.y;  // block (32,8)
    #pragma unroll
    for (int i = 0; i < 32; i += 8) {
        int bb = b0 + ty + i, tt = t0 + tx;
        if (tt < T_) tile[ty + i][tx] = feat[bb * T_ + tt];
    }
    __syncthreads();
    #pragma unroll
    for (int i = 0; i < 32; i += 8) {
        int tt = t0 + ty + i, bb = b0 + tx;
        if (tt < T_) featT[tt * B_ + bb] = tile[tx][ty + i];
    }
}

// ---------- main MFMA kernel ----------

__device__ __forceinline__ unsigned cvtpk_u(float a, float b) {
    v2h t = __builtin_amdgcn_cvt_pkrtz(a, b);
    unsigned u; __builtin_memcpy(&u, &t, 4);
    return u;
}
__device__ __forceinline__ unsigned u_from_v2h(v2h h) {
    unsigned u; __builtin_memcpy(&u, &h, 4); return u;
}

// SELU on a 4-f32 mfma accumulator quad -> packed f16 pair (next B frag).
// exp2 in f32; affine/min/max tail in packed f16 (v_pk_*). 12 inst/quad.
__device__ __forceinline__ uint2 selu_quad(f4v acc) {
    const v2h A2  = {(__fp16)( 1.6732632423543772f), (__fp16)( 1.6732632423543772f)};
    const v2h nA2 = {(__fp16)(-1.6732632423543772f), (__fp16)(-1.6732632423543772f)};
    const v2h L2h = {(__fp16)( 0.6931471805599453f), (__fp16)( 0.6931471805599453f)};
    const v2h Z2  = {(__fp16)0.0f, (__fp16)0.0f};
    float e0 = __builtin_amdgcn_exp2f(acc[0]);
    float e1 = __builtin_amdgcn_exp2f(acc[1]);
    float e2 = __builtin_amdgcn_exp2f(acc[2]);
    float e3 = __builtin_amdgcn_exp2f(acc[3]);
    v2h hu01 = __builtin_amdgcn_cvt_pkrtz(acc[0], acc[1]);
    v2h hu23 = __builtin_amdgcn_cvt_pkrtz(acc[2], acc[3]);
    v2h he01 = __builtin_amdgcn_cvt_pkrtz(e0, e1);
    v2h he23 = __builtin_amdgcn_cvt_pkrtz(e2, e3);
    v2h m01 = __builtin_elementwise_min(he01 * A2 + nA2, Z2);
    v2h m23 = __builtin_elementwise_min(he23 * A2 + nA2, Z2);
    v2h r01 = __builtin_elementwise_max(hu01, Z2) * L2h + m01;
    v2h r23 = __builtin_elementwise_max(hu23, Z2) * L2h + m23;
    return make_uint2(u_from_v2h(r01), u_from_v2h(r23));
}

__device__ __forceinline__ f4v mfma16(uint2 a, uint2 b, f4v c) {
    h4 ah, bh;
    __builtin_memcpy(&ah, &a, 8);
    __builtin_memcpy(&bh, &b, 8);
    return __builtin_amdgcn_mfma_f32_16x16x16f16(ah, bh, c, 0, 0, 0);
}

// Grid (B/64, G/16) = (4,1250), block = 512 threads = 8 waves, 1 pair/wave.
// r19 diagnosis: VALU 52%, MFMA 11%, occupancy 51% -> latency-bound with
// residency CAPPED by __launch_bounds__(512,4): w=4 waves/EU => k =
// 4*4/(512/64) = 2 blocks/CU = 16 waves/CU = 50%. (512,6) => 3 blocks/CU
// = 75% ceiling at ~85-VGPR budget (we use 36 — no spill risk). r16 showed
// 71% occupancy is reachable with this block shape; back then VALU-bound
// (67%) so it didn't pay — now stalls dominate and extra waves cover them.
__global__ __launch_bounds__(512, 6) void decoder_mfma(
    const float* __restrict__ featT,    // (T,B)
    const int*   __restrict__ tf_idx,   // (G,K)
    const float* __restrict__ W1,       // (G,W,K)
    const float* __restrict__ b1,       // (G,W)
    const float* __restrict__ Wm,       // (D,G,W,W)
    const float* __restrict__ bm,       // (D,G,W)
    const float* __restrict__ Wf,       // (G,W)
    const float* __restrict__ bf,       // (G,)
    float* __restrict__ out)            // (B,G)
{
    const float LOG2E = 1.44269504088896340736f;
    const float SCALE = 1.0507009873554805f;
    const float SL    = SCALE * LOG2E;

    const int tid  = threadIdx.x;
    const int lane = tid & 63;
    const int wv   = tid >> 6;              // 0..7 = pair within chunk
    const int bq   = blockIdx.x;             // batch quarter (64 rows)
    const int gc   = blockIdx.y;             // group-chunk of 16
    const char* fc = (const char*)featT;

    const int col   = lane & 15;             // A-row / B-col / C-col
    const int q     = lane >> 4;             // k/row quad
    const bool rlt8 = col < 8;
    const int kq    = (q & 1) * 4;           // k-offset within an 8-wide row

    __shared__ float smem[64][17];

    {
        const int pp = wv;
        const int p  = gc * 8 + pp;
        const int g0 = 2 * p, g1 = 2 * p + 1;
        const int ga = rlt8 ? g0 : g1;       // row-side group (A-row = col)
        const int ra = rlt8 ? col : col - 8;
        const int gq = (q < 2) ? g0 : g1;    // row-quad-side group (C rows)

        // --- gather bases: 8 addrs once; t-steps are imm offsets ---
        int4 id0 = *(const int4*)(tf_idx + g0 * K_ + 4 * q);
        int4 id1 = *(const int4*)(tf_idx + g1 * K_ + 4 * q);
        const unsigned vb0 = (unsigned)((bq * 64 + col) * 4);
        const char* p0 = fc + (((unsigned)id0.x << 10) + vb0);
        const char* p1 = fc + (((unsigned)id0.y << 10) + vb0);
        const char* p2 = fc + (((unsigned)id0.z << 10) + vb0);
        const char* p3 = fc + (((unsigned)id0.w << 10) + vb0);
        const char* p4 = fc + (((unsigned)id1.x << 10) + vb0);
        const char* p5 = fc + (((unsigned)id1.y << 10) + vb0);
        const char* p6 = fc + (((unsigned)id1.z << 10) + vb0);
        const char* p7 = fc + (((unsigned)id1.w << 10) + vb0);

        float xv[4][8];
        #pragma unroll
        for (int t = 0; t < 4; ++t) {
            xv[t][0] = *(const float*)(p0 + t * 64);
            xv[t][1] = *(const float*)(p1 + t * 64);
            xv[t][2] = *(const float*)(p2 + t * 64);
            xv[t][3] = *(const float*)(p3 + t * 64);
            xv[t][4] = *(const float*)(p4 + t * 64);
            xv[t][5] = *(const float*)(p5 + t * 64);
            xv[t][6] = *(const float*)(p6 + t * 64);
            xv[t][7] = *(const float*)(p7 + t * 64);
        }

        // --- A1: rows0-7 = LOG2E*W1_g0[w][k], rows8-15 = g1; split halves ---
        float4 w1v = *(const float4*)(W1 + ((long)ga * W_ + ra) * K_ + 4 * q);
        uint2 af;
        af.x = cvtpk_u(LOG2E * w1v.x, LOG2E * w1v.y);
        af.y = cvtpk_u(LOG2E * w1v.z, LOG2E * w1v.w);
        uint2 A1g0, A1g1;
        A1g0.x = rlt8 ? af.x : 0u;  A1g0.y = rlt8 ? af.y : 0u;
        A1g1.x = rlt8 ? 0u : af.x;  A1g1.y = rlt8 ? 0u : af.y;

        // --- AM0/AM1 block-diag: nonzero iff (col<8)==(q<2) ---
        const bool diag = (rlt8 == (q < 2));
        float4 wm0v = *(const float4*)(Wm + ((long)0 * G_ + ga) * 64 + ra * 8 + kq);
        float4 wm1v = *(const float4*)(Wm + ((long)1 * G_ + ga) * 64 + ra * 8 + kq);
        uint2 AM0, AM1;
        AM0.x = diag ? cvtpk_u(SL * wm0v.x, SL * wm0v.y) : 0u;
        AM0.y = diag ? cvtpk_u(SL * wm0v.z, SL * wm0v.w) : 0u;
        AM1.x = diag ? cvtpk_u(SL * wm1v.x, SL * wm1v.y) : 0u;
        AM1.y = diag ? cvtpk_u(SL * wm1v.z, SL * wm1v.w) : 0u;

        // --- AF: row0 = SCALE*Wf_g0 (k0-7); row8 = SCALE*Wf_g1 (k8-15) ---
        const bool fnz = (ra == 0) && diag;
        float4 wfv = *(const float4*)(Wf + (long)ga * W_ + kq);
        uint2 AF;
        AF.x = fnz ? cvtpk_u(SCALE * wfv.x, SCALE * wfv.y) : 0u;
        AF.y = fnz ? cvtpk_u(SCALE * wfv.z, SCALE * wfv.w) : 0u;

        // --- bias C-in frags (rows 4q..4q+3) ---
        float4 b1v  = *(const float4*)(b1 + (long)gq * W_ + kq);
        float4 bm0v = *(const float4*)(bm + ((long)0 * G_ + gq) * W_ + kq);
        float4 bm1v = *(const float4*)(bm + ((long)1 * G_ + gq) * W_ + kq);
        f4v bias1 = {LOG2E * b1v.x,  LOG2E * b1v.y,  LOG2E * b1v.z,  LOG2E * b1v.w};
        f4v bmf0  = {LOG2E * bm0v.x, LOG2E * bm0v.y, LOG2E * bm0v.z, LOG2E * bm0v.w};
        f4v bmf1  = {LOG2E * bm1v.x, LOG2E * bm1v.y, LOG2E * bm1v.z, LOG2E * bm1v.w};
        f4v bfin  = {0.f, 0.f, 0.f, 0.f};
        bfin[0] = ((q & 1) == 0) ? bf[gq] : 0.0f;   // rows 0 (g0) and 8 (g1)

        // --- 4 register-disjoint chains: compiler interleaves for ILP ---
        #pragma unroll
        for (int t = 0; t < 4; ++t) {
            uint2 bg0, bg1;
            bg0.x = cvtpk_u(xv[t][0], xv[t][1]); bg0.y = cvtpk_u(xv[t][2], xv[t][3]);
            bg1.x = cvtpk_u(xv[t][4], xv[t][5]); bg1.y = cvtpk_u(xv[t][6], xv[t][7]);

            f4v acc = mfma16(A1g0, bg0, bias1);
            acc     = mfma16(A1g1, bg1, acc);

            uint2 bh = selu_quad(acc);
            acc = mfma16(AM0, bh, bmf0);
            bh  = selu_quad(acc);
            acc = mfma16(AM1, bh, bmf1);
            bh  = selu_quad(acc);
            acc = mfma16(AF, bh, bfin);

            // D row0 (g even) in lanes q==0, row8 (g odd) in q==2
            if (!(q & 1))
                smem[t * 16 + col][2 * pp + ((q >> 1) & 1)] = acc[0];
        }
    }

    __syncthreads();

    // epilogue: 8 threads per batch row, float2 each -> full 64B lines
    {
        const int row = tid >> 3;           // 0..63 (local batch row)
        const int seg = tid & 7;            // 8B segment within the line
        float2 v = make_float2(smem[row][seg * 2 + 0], smem[row][seg * 2 + 1]);
        *(float2*)(out + (long)(bq * 64 + row) * G_ + gc * 16 + seg * 2) = v;
    }
}

// ---------- fallback (no workspace): direct scalar path ----------
#define FGPB 4
__device__ __forceinline__ float selu_f(float x) {
    const float scale = 1.0507009873554805f;
    const float sa    = 1.7580993408473766f;
    float e   = __expf(x);
    float neg = fmaf(sa, e, -sa);
    return x > 0.0f ? scale * x : neg;
}
template<bool TRANSPOSED>
__global__ __launch_bounds__(256) void decoder_kernel(
    const float* __restrict__ featsrc, const int* __restrict__ tf_idx,
    const float* __restrict__ W1, const float* __restrict__ b1,
    const float* __restrict__ Wm, const float* __restrict__ bm,
    const float* __restrict__ Wf, const float* __restrict__ bf,
    float* __restrict__ out)
{
    const int b  = threadIdx.x;
    const int g0 = blockIdx.x * FGPB;
    float res[FGPB];
    #pragma unroll
    for (int gi = 0; gi < FGPB; ++gi) {
        const int g = g0 + gi;
        float xg[K_];
        #pragma unroll
        for (int k = 0; k < K_; ++k) {
            int t = tf_idx[g * K_ + k];
            xg[k] = TRANSPOSED ? featsrc[t * B_ + b] : featsrc[b * T_ + t];
        }
        float h[W_];
        #pragma unroll
        for (int w = 0; w < W_; ++w) {
            float acc = b1[g * W_ + w];
            #pragma unroll
            for (int k = 0; k < K_; ++k)
                acc = fmaf(xg[k], W1[(g * W_ + w) * K_ + k], acc);
            h[w] = selu_f(acc);
        }
        #pragma unroll
        for (int d = 0; d < D_; ++d) {
            const float* wmd = Wm + ((size_t)d * G_ + g) * (W_ * W_);
            const float* bmd = bm + ((size_t)d * G_ + g) * W_;
            float h2[W_];
            #pragma unroll
            for (int v = 0; v < W_; ++v) {
                float acc = bmd[v];
                #pragma unroll
                for (int w = 0; w < W_; ++w)
                    acc = fmaf(h[w], wmd[v * W_ + w], acc);
                h2[v] = selu_f(acc);
            }
            #pragma unroll
            for (int w = 0; w < W_; ++w) h[w] = h2[w];
        }
        float acc = bf[g];
        #pragma unroll
        for (int w = 0; w < W_; ++w)
            acc = fmaf(h[w], Wf[g * W_ + w], acc);
        res[gi] = acc;
    }
    float4* o = (float4*)(out + (size_t)b * G_ + g0);
    o[0] = make_float4(res[0], res[1], res[2], res[3]);
}

extern "C" void kernel_launch(void* const* d_in, const int* in_sizes, int n_in,
                              void* d_out, int out_size, void* d_ws, size_t ws_size,
                              hipStream_t stream) {
    const float* feat   = (const float*)d_in[0];
    const int*   tf_idx = (const int*)  d_in[1];
    const float* W1     = (const float*)d_in[2];
    const float* b1     = (const float*)d_in[3];
    const float* Wm     = (const float*)d_in[4];
    const float* bm     = (const float*)d_in[5];
    const float* Wf     = (const float*)d_in[6];
    const float* bf     = (const float*)d_in[7];
    float* out = (float*)d_out;

    const size_t featT_b = (size_t)T_ * B_ * sizeof(float);   // 1.536 MB

    if (ws_size >= featT_b) {
        float* featT = (float*)d_ws;
        hipLaunchKernelGGL(transpose_feat, dim3((T_ + 31) / 32, B_ / 32),
                           dim3(32, 8), 0, stream, feat, featT);
        hipLaunchKernelGGL(decoder_mfma, dim3(B_ / 64, G_ / 16), dim3(512), 0,
                           stream, featT, tf_idx, W1, b1, Wm, bm, Wf, bf, out);
    } else {
        hipLaunchKernelGGL((decoder_kernel<false>), dim3(G_ / FGPB), dim3(B_), 0,
                           stream, feat, tf_idx, W1, b1, Wm, bm, Wf, bf, out);
    }
}

// Round 21
// 44.146 us; speedup vs baseline: 1.4544x; 1.0443x over previous
//
#include <hip/hip_runtime.h>
#include <hip/hip_fp16.h>

#define G_ 20000
#define W_ 8
#define K_ 16
#define T_ 1500
#define B_ 256
#define D_ 2

using h4  = __attribute__((ext_vector_type(4))) __fp16;
using f4v = __attribute__((ext_vector_type(4))) float;
typedef decltype(__builtin_amdgcn_cvt_pkrtz(0.0f, 0.0f)) v2h;  // __fp16 x2

// ---------- prep: feat (B,T) -> featT (T,B) ----------
__global__ void transpose_feat(const float* __restrict__ feat,
                               float* __restrict__ featT) {
    __shared__ float tile[32][33];
    int t0 = blockIdx.x * 32;
    int b0 = blockIdx.y * 32;
    int tx = threadIdx.x, ty = threadIdx.y;  // block (32,8)
    #pragma unroll
    for (int i = 0; i < 32; i += 8) {
        int bb = b0 + ty + i, tt = t0 + tx;
        if (tt < T_) tile[ty + i][tx] = feat[bb * T_ + tt];
    }
    __syncthreads();
    #pragma unroll
    for (int i = 0; i < 32; i += 8) {
        int tt = t0 + ty + i, bb = b0 + tx;
        if (tt < T_) featT[tt * B_ + bb] = tile[tx][ty + i];
    }
}

// ---------- main MFMA kernel ----------

__device__ __forceinline__ unsigned cvtpk_u(float a, float b) {
    v2h t = __builtin_amdgcn_cvt_pkrtz(a, b);
    unsigned u; __builtin_memcpy(&u, &t, 4);
    return u;
}
__device__ __forceinline__ unsigned u_from_v2h(v2h h) {
    unsigned u; __builtin_memcpy(&u, &h, 4); return u;
}

// SELU on a 4-f32 mfma accumulator quad -> packed f16 pair (next B frag).
// exp2 in f32; affine/min/max tail in packed f16 (v_pk_*). 12 inst/quad.
__device__ __forceinline__ uint2 selu_quad(f4v acc) {
    const v2h A2  = {(__fp16)( 1.6732632423543772f), (__fp16)( 1.6732632423543772f)};
    const v2h nA2 = {(__fp16)(-1.6732632423543772f), (__fp16)(-1.6732632423543772f)};
    const v2h L2h = {(__fp16)( 0.6931471805599453f), (__fp16)( 0.6931471805599453f)};
    const v2h Z2  = {(__fp16)0.0f, (__fp16)0.0f};
    float e0 = __builtin_amdgcn_exp2f(acc[0]);
    float e1 = __builtin_amdgcn_exp2f(acc[1]);
    float e2 = __builtin_amdgcn_exp2f(acc[2]);
    float e3 = __builtin_amdgcn_exp2f(acc[3]);
    v2h hu01 = __builtin_amdgcn_cvt_pkrtz(acc[0], acc[1]);
    v2h hu23 = __builtin_amdgcn_cvt_pkrtz(acc[2], acc[3]);
    v2h he01 = __builtin_amdgcn_cvt_pkrtz(e0, e1);
    v2h he23 = __builtin_amdgcn_cvt_pkrtz(e2, e3);
    v2h m01 = __builtin_elementwise_min(he01 * A2 + nA2, Z2);
    v2h m23 = __builtin_elementwise_min(he23 * A2 + nA2, Z2);
    v2h r01 = __builtin_elementwise_max(hu01, Z2) * L2h + m01;
    v2h r23 = __builtin_elementwise_max(hu23, Z2) * L2h + m23;
    return make_uint2(u_from_v2h(r01), u_from_v2h(r23));
}

__device__ __forceinline__ f4v mfma16(uint2 a, uint2 b, f4v c) {
    h4 ah, bh;
    __builtin_memcpy(&ah, &a, 8);
    __builtin_memcpy(&bh, &b, 8);
    return __builtin_amdgcn_mfma_f32_16x16x16f16(ah, bh, c, 0, 0, 0);
}

// Grid (B/128, G/16) = (2,1250) = 2500 blocks; block = 512 threads = 8
// waves; wave = 1 group-pair x 8 batch-tiles (128 rows).
// r20 lesson: occupancy knobs are exhausted (52% across 3 declarations,
// r16's 71% didn't help) — the lever left is per-wave fixed cost. This
// round amortizes frag-build + weight loads over 8 chains instead of 4
// (~-10% total inst) and halves weight re-fetch (FETCH 49 -> ~37MB).
// All 64 gathers hoisted (xv[8][8], 64 VGPR) for deep ILP; (512,4) gives
// the 128-VGPR budget.
__global__ __launch_bounds__(512, 4) void decoder_mfma(
    const float* __restrict__ featT,    // (T,B)
    const int*   __restrict__ tf_idx,   // (G,K)
    const float* __restrict__ W1,       // (G,W,K)
    const float* __restrict__ b1,       // (G,W)
    const float* __restrict__ Wm,       // (D,G,W,W)
    const float* __restrict__ bm,       // (D,G,W)
    const float* __restrict__ Wf,       // (G,W)
    const float* __restrict__ bf,       // (G,)
    float* __restrict__ out)            // (B,G)
{
    const float LOG2E = 1.44269504088896340736f;
    const float SCALE = 1.0507009873554805f;
    const float SL    = SCALE * LOG2E;

    const int tid  = threadIdx.x;
    const int lane = tid & 63;
    const int wv   = tid >> 6;              // 0..7 = pair within chunk
    const int bh   = blockIdx.x;             // batch half (128 rows)
    const int gc   = blockIdx.y;             // group-chunk of 16
    const char* fc = (const char*)featT;

    const int col   = lane & 15;             // A-row / B-col / C-col
    const int q     = lane >> 4;             // k/row quad
    const bool rlt8 = col < 8;
    const int kq    = (q & 1) * 4;           // k-offset within an 8-wide row

    __shared__ float smem[128][17];

    {
        const int pp = wv;
        const int p  = gc * 8 + pp;
        const int g0 = 2 * p, g1 = 2 * p + 1;
        const int ga = rlt8 ? g0 : g1;       // row-side group (A-row = col)
        const int ra = rlt8 ? col : col - 8;
        const int gq = (q < 2) ? g0 : g1;    // row-quad-side group (C rows)

        // --- gather bases: 8 addrs once; t-steps are imm offsets ---
        int4 id0 = *(const int4*)(tf_idx + g0 * K_ + 4 * q);
        int4 id1 = *(const int4*)(tf_idx + g1 * K_ + 4 * q);
        const unsigned vb0 = (unsigned)((bh * 128 + col) * 4);
        const char* p0 = fc + (((unsigned)id0.x << 10) + vb0);
        const char* p1 = fc + (((unsigned)id0.y << 10) + vb0);
        const char* p2 = fc + (((unsigned)id0.z << 10) + vb0);
        const char* p3 = fc + (((unsigned)id0.w << 10) + vb0);
        const char* p4 = fc + (((unsigned)id1.x << 10) + vb0);
        const char* p5 = fc + (((unsigned)id1.y << 10) + vb0);
        const char* p6 = fc + (((unsigned)id1.z << 10) + vb0);
        const char* p7 = fc + (((unsigned)id1.w << 10) + vb0);

        // --- hoisted gathers: 8 tiles x 8 values (64 VGPR), deep ILP ---
        float xv[8][8];
        #pragma unroll
        for (int t = 0; t < 8; ++t) {
            xv[t][0] = *(const float*)(p0 + t * 64);
            xv[t][1] = *(const float*)(p1 + t * 64);
            xv[t][2] = *(const float*)(p2 + t * 64);
            xv[t][3] = *(const float*)(p3 + t * 64);
            xv[t][4] = *(const float*)(p4 + t * 64);
            xv[t][5] = *(const float*)(p5 + t * 64);
            xv[t][6] = *(const float*)(p6 + t * 64);
            xv[t][7] = *(const float*)(p7 + t * 64);
        }

        // --- A1: rows0-7 = LOG2E*W1_g0[w][k], rows8-15 = g1; split halves ---
        float4 w1v = *(const float4*)(W1 + ((long)ga * W_ + ra) * K_ + 4 * q);
        uint2 af;
        af.x = cvtpk_u(LOG2E * w1v.x, LOG2E * w1v.y);
        af.y = cvtpk_u(LOG2E * w1v.z, LOG2E * w1v.w);
        uint2 A1g0, A1g1;
        A1g0.x = rlt8 ? af.x : 0u;  A1g0.y = rlt8 ? af.y : 0u;
        A1g1.x = rlt8 ? 0u : af.x;  A1g1.y = rlt8 ? 0u : af.y;

        // --- AM0/AM1 block-diag: nonzero iff (col<8)==(q<2) ---
        const bool diag = (rlt8 == (q < 2));
        float4 wm0v = *(const float4*)(Wm + ((long)0 * G_ + ga) * 64 + ra * 8 + kq);
        float4 wm1v = *(const float4*)(Wm + ((long)1 * G_ + ga) * 64 + ra * 8 + kq);
        uint2 AM0, AM1;
        AM0.x = diag ? cvtpk_u(SL * wm0v.x, SL * wm0v.y) : 0u;
        AM0.y = diag ? cvtpk_u(SL * wm0v.z, SL * wm0v.w) : 0u;
        AM1.x = diag ? cvtpk_u(SL * wm1v.x, SL * wm1v.y) : 0u;
        AM1.y = diag ? cvtpk_u(SL * wm1v.z, SL * wm1v.w) : 0u;

        // --- AF: row0 = SCALE*Wf_g0 (k0-7); row8 = SCALE*Wf_g1 (k8-15) ---
        const bool fnz = (ra == 0) && diag;
        float4 wfv = *(const float4*)(Wf + (long)ga * W_ + kq);
        uint2 AF;
        AF.x = fnz ? cvtpk_u(SCALE * wfv.x, SCALE * wfv.y) : 0u;
        AF.y = fnz ? cvtpk_u(SCALE * wfv.z, SCALE * wfv.w) : 0u;

        // --- bias C-in frags (rows 4q..4q+3) ---
        float4 b1v  = *(const float4*)(b1 + (long)gq * W_ + kq);
        float4 bm0v = *(const float4*)(bm + ((long)0 * G_ + gq) * W_ + kq);
        float4 bm1v = *(const float4*)(bm + ((long)1 * G_ + gq) * W_ + kq);
        f4v bias1 = {LOG2E * b1v.x,  LOG2E * b1v.y,  LOG2E * b1v.z,  LOG2E * b1v.w};
        f4v bmf0  = {LOG2E * bm0v.x, LOG2E * bm0v.y, LOG2E * bm0v.z, LOG2E * bm0v.w};
        f4v bmf1  = {LOG2E * bm1v.x, LOG2E * bm1v.y, LOG2E * bm1v.z, LOG2E * bm1v.w};
        f4v bfin  = {0.f, 0.f, 0.f, 0.f};
        bfin[0] = ((q & 1) == 0) ? bf[gq] : 0.0f;   // rows 0 (g0) and 8 (g1)

        // --- 8 register-disjoint chains: compiler interleaves for ILP ---
        #pragma unroll
        for (int t = 0; t < 8; ++t) {
            uint2 bg0, bg1;
            bg0.x = cvtpk_u(xv[t][0], xv[t][1]); bg0.y = cvtpk_u(xv[t][2], xv[t][3]);
            bg1.x = cvtpk_u(xv[t][4], xv[t][5]); bg1.y = cvtpk_u(xv[t][6], xv[t][7]);

            f4v acc = mfma16(A1g0, bg0, bias1);
            acc     = mfma16(A1g1, bg1, acc);

            uint2 bh2 = selu_quad(acc);
            acc = mfma16(AM0, bh2, bmf0);
            bh2 = selu_quad(acc);
            acc = mfma16(AM1, bh2, bmf1);
            bh2 = selu_quad(acc);
            acc = mfma16(AF, bh2, bfin);

            // D row0 (g even) in lanes q==0, row8 (g odd) in q==2
            if (!(q & 1))
                smem[t * 16 + col][2 * pp + ((q >> 1) & 1)] = acc[0];
        }
    }

    __syncthreads();

    // epilogue: 4 threads per batch row (float4 each) -> full 64B lines
    {
        const int row = tid >> 2;           // 0..127 (local batch row)
        const int seg = tid & 3;            // 16B segment within the line
        float4 v = make_float4(smem[row][seg * 4 + 0], smem[row][seg * 4 + 1],
                               smem[row][seg * 4 + 2], smem[row][seg * 4 + 3]);
        *(float4*)(out + (long)(bh * 128 + row) * G_ + gc * 16 + seg * 4) = v;
    }
}

// ---------- fallback (no workspace): direct scalar path ----------
#define FGPB 4
__device__ __forceinline__ float selu_f(float x) {
    const float scale = 1.0507009873554805f;
    const float sa    = 1.7580993408473766f;
    float e   = __expf(x);
    float neg = fmaf(sa, e, -sa);
    return x > 0.0f ? scale * x : neg;
}
template<bool TRANSPOSED>
__global__ __launch_bounds__(256) void decoder_kernel(
    const float* __restrict__ featsrc, const int* __restrict__ tf_idx,
    const float* __restrict__ W1, const float* __restrict__ b1,
    const float* __restrict__ Wm, const float* __restrict__ bm,
    const float* __restrict__ Wf, const float* __restrict__ bf,
    float* __restrict__ out)
{
    const int b  = threadIdx.x;
    const int g0 = blockIdx.x * FGPB;
    float res[FGPB];
    #pragma unroll
    for (int gi = 0; gi < FGPB; ++gi) {
        const int g = g0 + gi;
        float xg[K_];
        #pragma unroll
        for (int k = 0; k < K_; ++k) {
            int t = tf_idx[g * K_ + k];
            xg[k] = TRANSPOSED ? featsrc[t * B_ + b] : featsrc[b * T_ + t];
        }
        float h[W_];
        #pragma unroll
        for (int w = 0; w < W_; ++w) {
            float acc = b1[g * W_ + w];
            #pragma unroll
            for (int k = 0; k < K_; ++k)
                acc = fmaf(xg[k], W1[(g * W_ + w) * K_ + k], acc);
            h[w] = selu_f(acc);
        }
        #pragma unroll
        for (int d = 0; d < D_; ++d) {
            const float* wmd = Wm + ((size_t)d * G_ + g) * (W_ * W_);
            const float* bmd = bm + ((size_t)d * G_ + g) * W_;
            float h2[W_];
            #pragma unroll
            for (int v = 0; v < W_; ++v) {
                float acc = bmd[v];
                #pragma unroll
                for (int w = 0; w < W_; ++w)
                    acc = fmaf(h[w], wmd[v * W_ + w], acc);
                h2[v] = selu_f(acc);
            }
            #pragma unroll
            for (int w = 0; w < W_; ++w) h[w] = h2[w];
        }
        float acc = bf[g];
        #pragma unroll
        for (int w = 0; w < W_; ++w)
            acc = fmaf(h[w], Wf[g * W_ + w], acc);
        res[gi] = acc;
    }
    float4* o = (float4*)(out + (size_t)b * G_ + g0);
    o[0] = make_float4(res[0], res[1], res[2], res[3]);
}

extern "C" void kernel_launch(void* const* d_in, const int* in_sizes, int n_in,
                              void* d_out, int out_size, void* d_ws, size_t ws_size,
                              hipStream_t stream) {
    const float* feat   = (const float*)d_in[0];
    const int*   tf_idx = (const int*)  d_in[1];
    const float* W1     = (const float*)d_in[2];
    const float* b1     = (const float*)d_in[3];
    const float* Wm     = (const float*)d_in[4];
    const float* bm     = (const float*)d_in[5];
    const float* Wf     = (const float*)d_in[6];
    const float* bf     = (const float*)d_in[7];
    float* out = (float*)d_out;

    const size_t featT_b = (size_t)T_ * B_ * sizeof(float);   // 1.536 MB

    if (ws_size >= featT_b) {
        float* featT = (float*)d_ws;
        hipLaunchKernelGGL(transpose_feat, dim3((T_ + 31) / 32, B_ / 32),
                           dim3(32, 8), 0, stream, feat, featT);
        hipLaunchKernelGGL(decoder_mfma, dim3(B_ / 128, G_ / 16), dim3(512), 0,
                           stream, featT, tf_idx, W1, b1, Wm, bm, Wf, bf, out);
    } else {
        hipLaunchKernelGGL((decoder_kernel<false>), dim3(G_ / FGPB), dim3(B_), 0,
                           stream, feat, tf_idx, W1, b1, Wm, bm, Wf, bf, out);
    }
}